// Round 12
// baseline (234.996 us; speedup 1.0000x reference)
//
#include <hip/hip_runtime.h>

typedef __attribute__((ext_vector_type(2))) float f32x2;
typedef __attribute__((ext_vector_type(4))) float f32x4;
typedef __attribute__((ext_vector_type(16))) float f32x16;
typedef __attribute__((ext_vector_type(8))) __bf16 bf16x8;
typedef __attribute__((ext_vector_type(4))) __bf16 bf16x4;
typedef __attribute__((ext_vector_type(2))) __bf16 bf16x2;
typedef __attribute__((ext_vector_type(4))) unsigned int u32x4;

#define DEVI __device__ __forceinline__

static constexpr int QLEN = 2048, BSZ = 4, DM = 1024, NH = 16, DH = 64;
static constexpr int MROWS = QLEN * BSZ;       // 8192
static constexpr long OSZ  = (long)MROWS * DM; // 8388608 elements per output tensor
static constexpr float SCL2E = 0.125f * 1.4426950408889634f; // SCALE * log2(e), folded into Q

DEVI void gload_lds16(const void* g, void* l) {
  __builtin_amdgcn_global_load_lds(
      (__attribute__((address_space(1))) void*)(size_t)g,
      (__attribute__((address_space(3))) void*)l, 16, 0, 0);
}

DEVI f32x16 zero16() {
  f32x16 v;
#pragma unroll
  for (int i = 0; i < 16; ++i) v[i] = 0.f;
  return v;
}

DEVI unsigned pack_bf16(float lo, float hi) {
  bf16x2 v = { (__bf16)lo, (__bf16)hi };
  return __builtin_bit_cast(unsigned, v);
}

struct f2x8 { f32x2 h[8]; };

DEVI f32x2 pk_add(f32x2 a, f32x2 b) {
  f32x2 d;
  asm("v_pk_add_f32 %0, %1, %2" : "=v"(d) : "v"(a), "v"(b));
  return d;
}

// ------------------------------------------------- prep: x fp32->bf16 + 4x wtrans
__global__ void k_prep(const float* __restrict__ x, __bf16* __restrict__ xb,
                       const float* __restrict__ W0, const float* __restrict__ W1,
                       const float* __restrict__ W2, const float* __restrict__ W3,
                       __bf16* __restrict__ WtAll) {
  __shared__ float tile[64][65];
  const int t = threadIdx.x;
  if (blockIdx.x < 1024) {
    const int g = blockIdx.x >> 8;     // 0..3
    const float* W = g == 0 ? W0 : (g == 1 ? W1 : (g == 2 ? W2 : W3));
    __bf16* Wt = WtAll + (size_t)g * DM * DM;
    const int bid = blockIdx.x & 255;
    const int tk = bid >> 4;
    const int tn = bid & 15;
    const int r = t >> 4;
    const int c4 = (t & 15) << 2;
#pragma unroll
    for (int i = 0; i < 4; ++i) {
      const float4 v = *(const float4*)&W[(size_t)(tk * 64 + r + i * 16) * DM + tn * 64 + c4];
      tile[r + i * 16][c4 + 0] = v.x;
      tile[r + i * 16][c4 + 1] = v.y;
      tile[r + i * 16][c4 + 2] = v.z;
      tile[r + i * 16][c4 + 3] = v.w;
    }
    __syncthreads();
#pragma unroll
    for (int i = 0; i < 4; ++i) {
      const int n = r + i * 16;
      bf16x4 o = { (__bf16)tile[c4 + 0][n], (__bf16)tile[c4 + 1][n],
                   (__bf16)tile[c4 + 2][n], (__bf16)tile[c4 + 3][n] };
      *(bf16x4*)&Wt[(size_t)(tn * 64 + n) * DM + tk * 64 + c4] = o;
    }
  } else {
    const int n4 = (int)(OSZ / 4);
    int i = (blockIdx.x - 1024) * 256 + t;
    for (; i < n4; i += 2048 * 256) {
      const float4 v = ((const float4*)x)[i];
      bf16x4 o = { (__bf16)v.x, (__bf16)v.y, (__bf16)v.z, (__bf16)v.w };
      ((bf16x4*)xb)[i] = o;
    }
  }
}

// ------------------------------------------------- V bf16 -> slab-tiled VT2
__global__ __launch_bounds__(256, 4) void k_vtrans(const __bf16* __restrict__ vb,
                                                   __bf16* __restrict__ VT) {
  __shared__ __bf16 tile[128 * 72];   // row stride 72 bf16 (36 dw)
  const int t = threadIdx.x;
  const int bh = blockIdx.x >> 4;
  const int s0 = (blockIdx.x & 15) * 128;
  const int b = bh >> 4, h = bh & 15;

  {
    const int r = t >> 1, hh = t & 1;
    const __bf16* src = vb + (size_t)((s0 + r) * 4 + b) * DM + h * 64 + hh * 32;
    __bf16* dst = tile + r * 72 + hh * 32;
#pragma unroll
    for (int k = 0; k < 4; ++k)
      *(bf16x8*)(dst + k * 8) = *(const bf16x8*)(src + k * 8);
  }
  __syncthreads();

  const int l = t & 63;
  const int w = t >> 6;
  const int hf = l >> 5;
#pragma unroll
  for (int gi = 0; gi < 4; ++gi) {
    const int idx = w * 4 + gi;
    const int ktl = idx >> 3;
    const int fi = idx & 7;
    const int jc = fi >> 1, dh = fi & 1;
    const int d = dh * 32 + (l & 31);
    const int j8 = ktl * 64 + jc * 16 + hf * 8;
    bf16x8 pk;
#pragma unroll
    for (int jj = 0; jj < 8; ++jj) pk[jj] = tile[(j8 + jj) * 72 + d];
    const int kt_g = (blockIdx.x & 15) * 2 + ktl;
    *(bf16x8*)&VT[(size_t)(((bh * 32 + kt_g) * 8 + fi) * 64 + l) * 8] = pk;
  }
}

// ---------------------------------------------------------------- GEMM core (128^2, m97 structure)
DEVI void gemm_tile_core(const __bf16* __restrict__ A, const __bf16* __restrict__ Bt,
                         char* Alds, char* Blds, int m0, int n0, int t,
                         f32x4 (&acc)[4][4]) {
  constexpr int K = 1024;
  const int l = t & 63;
  const int w = t >> 6;
  const int wr = w >> 1, wc = w & 1;

  int a_addr[2][4], b_addr[2][4];
#pragma unroll
  for (int s = 0; s < 2; ++s)
#pragma unroll
    for (int f = 0; f < 4; ++f) {
      const int ca = s * 64 + ((l >> 4) << 4);
      const int ra = wr * 64 + f * 16 + (l & 15);
      a_addr[s][f] = ra * 128 + (ca ^ ((ra & 7) << 4));
      const int rb = wc * 64 + f * 16 + (l & 15);
      b_addr[s][f] = rb * 128 + (ca ^ ((rb & 7) << 4));
    }

  int g_row[4], g_col[4];
#pragma unroll
  for (int i = 0; i < 4; ++i) {
    const int g = i * 256 + t;
    g_row[i] = g >> 3;
    g_col[i] = ((g & 7) ^ (g_row[i] & 7)) * 8;
  }

  for (int kt = 0; kt < K / 64; ++kt) {
#pragma unroll
    for (int i = 0; i < 4; ++i) {
      gload_lds16(A + (size_t)(m0 + g_row[i]) * K + kt * 64 + g_col[i],
                  Alds + (size_t)(i * 256 + t) * 16);
      gload_lds16(Bt + (size_t)(n0 + g_row[i]) * K + kt * 64 + g_col[i],
                  Blds + (size_t)(i * 256 + t) * 16);
    }
    __syncthreads();
#pragma unroll
    for (int s = 0; s < 2; ++s) {
      bf16x8 af[4], bfr[4];
#pragma unroll
      for (int f = 0; f < 4; ++f) {
        af[f]  = *(const bf16x8*)(Alds + a_addr[s][f]);
        bfr[f] = *(const bf16x8*)(Blds + b_addr[s][f]);
      }
      __builtin_amdgcn_s_setprio(1);
#pragma unroll
      for (int mi = 0; mi < 4; ++mi)
#pragma unroll
        for (int ni = 0; ni < 4; ++ni)
          acc[mi][ni] = __builtin_amdgcn_mfma_f32_16x16x32_bf16(af[mi], bfr[ni], acc[mi][ni], 0, 0, 0);
      __builtin_amdgcn_s_setprio(0);
    }
    __syncthreads();
  }
}

// Final GEMM: N=1024 single fp32 output (unchanged, verified)
__global__ __launch_bounds__(256, 3) void k_gemm(
    const __bf16* __restrict__ A, const __bf16* __restrict__ Bt,
    const float* __restrict__ bias, float* __restrict__ Cf) {
  __shared__ alignas(16) char lds[32768];
  const int t = threadIdx.x;
  const int l = t & 63;
  const int w = t >> 6;
  const int n0 = (blockIdx.x & 7) * 128;
  const int m0 = (blockIdx.x >> 3) * 128;
  const int wr = w >> 1, wc = w & 1;

  f32x4 acc[4][4];
#pragma unroll
  for (int i = 0; i < 4; ++i)
#pragma unroll
    for (int j = 0; j < 4; ++j) acc[i][j] = (f32x4){0.f, 0.f, 0.f, 0.f};

  gemm_tile_core(A, Bt, lds, lds + 16384, m0, n0, t, acc);

  const int rowb = m0 + wr * 64 + ((l >> 4) << 2);
  const int colb = n0 + wc * 64 + (l & 15);
#pragma unroll
  for (int ni = 0; ni < 4; ++ni) {
    const float bv = bias[colb + ni * 16];
#pragma unroll
    for (int mi = 0; mi < 4; ++mi)
#pragma unroll
      for (int r = 0; r < 4; ++r)
        Cf[(size_t)(rowb + mi * 16 + r) * 1024 + colb + ni * 16] = acc[mi][ni][r] + bv;
  }
}

// ---------------------------------------------------------------- QKV GEMM, 8-phase 256^2
// 512 thr = 8 waves (2M x 4N); BK=64; LDS 128KB = 2 dbuf x (A 2x16KB + B 2x16KB).
// Per K-tile: 4 phases {ds-read quadrant, stage 1 half-tile, s_barrier, lgkmcnt(0),
// 16 MFMA, s_barrier}. Staging: A(T+1) at ph0/1 -> buf[(T+1)&1]; B(T+2) at ph2/3 ->
// buf[T&1] (B of T dead after ph1, A dead after ph2). Counted vmcnt(4) once per
// K-tile at ph3 (vmcnt(0) for T>=14). RoPE/bias epilogue as before.
__global__ __launch_bounds__(512, 2) void k_gemm_qkv8(
    const __bf16* __restrict__ A, const __bf16* __restrict__ Bt,
    const float* __restrict__ bq, const float* __restrict__ bk, const float* __restrict__ bv,
    const float* __restrict__ fc, const float* __restrict__ fs,
    float* __restrict__ ok, float* __restrict__ ov,
    __bf16* __restrict__ qr, __bf16* __restrict__ kr, __bf16* __restrict__ vb) {
  __shared__ alignas(16) char lds[131072];
  const int t = threadIdx.x;          // 0..511
  const int l = t & 63;
  const int wid = t >> 6;             // 0..7
  const int wr = wid >> 2;            // 0..1  (M half)
  const int wc = wid & 3;             // 0..3  (N quarter)

  const int swz = (blockIdx.x & 7) * 48 + (blockIdx.x >> 3);  // bijective, 384%8==0
  const int mt = swz & 31;            // 0..31
  const int nt = swz >> 5;            // 0..11

  // staging per-thread source offsets (granule g = i*512+t; row=g>>3; inverse swizzle)
  size_t aoff[2], boff[2];
#pragma unroll
  for (int i = 0; i < 2; ++i) {
    const int g = i * 512 + t;
    const int row = g >> 3;                    // 0..127
    const int c16 = (g & 7) ^ (row & 7);
    aoff[i] = (size_t)(mt * 256 + row) * 1024 + c16 * 8;
    boff[i] = (size_t)(nt * 256 + row) * 1024 + c16 * 8;
  }

  // fragment read terms
  const int rowbyte = (l & 15) * 128;
  const int ct0 = (((l >> 4) << 4)) ^ ((l & 7) << 4);
  const int ct1 = (64 + ((l >> 4) << 4)) ^ ((l & 7) << 4);

  f32x4 acc[8][4];
#pragma unroll
  for (int i = 0; i < 8; ++i)
#pragma unroll
    for (int j = 0; j < 4; ++j) acc[i][j] = (f32x4){0.f, 0.f, 0.f, 0.f};

  bf16x8 af[2][4], bf[2][4];

  auto stageA = [&](int d, int h, int kt) {
#pragma unroll
    for (int i = 0; i < 2; ++i)
      gload_lds16(A + aoff[i] + (size_t)h * 131072 + kt * 64,
                  lds + d * 65536 + h * 16384 + (size_t)(i * 512 + t) * 16);
  };
  auto stageB = [&](int d, int h, int kt) {
#pragma unroll
    for (int i = 0; i < 2; ++i)
      gload_lds16(Bt + boff[i] + (size_t)h * 131072 + kt * 64,
                  lds + d * 65536 + 32768 + h * 16384 + (size_t)(i * 512 + t) * 16);
  };

  // ---- prologue: A(t0), B(t0), B(t1); ensure t0 complete (vmcnt(4) = allow B(t1))
  stageA(0, 0, 0); stageA(0, 1, 0);
  stageB(0, 0, 0); stageB(0, 1, 0);
  stageB(1, 0, 1); stageB(1, 1, 1);
  asm volatile("s_waitcnt vmcnt(4)");
  __builtin_amdgcn_s_barrier();

  auto do_tile = [&](int T, int cur) {
    const char* ab = lds + cur * 65536 + wr * 16384 + rowbyte;
    const char* bb = lds + cur * 65536 + 32768 + (wc >> 1) * 16384 + (wc & 1) * 8192 + rowbyte;
    const int nxt = cur ^ 1;

    // ---- phase 0: read A(mh0) + B(n0,n1); stage A(T+1) h0
#pragma unroll
    for (int ks = 0; ks < 2; ++ks) {
      const int ct = ks ? ct1 : ct0;
#pragma unroll
      for (int mm = 0; mm < 4; ++mm) af[ks][mm] = *(const bf16x8*)(ab + mm * 2048 + ct);
#pragma unroll
      for (int nn = 0; nn < 2; ++nn) bf[ks][nn] = *(const bf16x8*)(bb + nn * 2048 + ct);
    }
    if (T + 1 < 16) stageA(nxt, 0, T + 1);
    __builtin_amdgcn_s_barrier();
    asm volatile("s_waitcnt lgkmcnt(0)");
    __builtin_amdgcn_sched_barrier(0);
    __builtin_amdgcn_s_setprio(1);
#pragma unroll
    for (int ks = 0; ks < 2; ++ks)
#pragma unroll
      for (int mm = 0; mm < 4; ++mm)
#pragma unroll
        for (int nn = 0; nn < 2; ++nn)
          acc[mm][nn] = __builtin_amdgcn_mfma_f32_16x16x32_bf16(af[ks][mm], bf[ks][nn], acc[mm][nn], 0, 0, 0);
    __builtin_amdgcn_s_setprio(0);
    __builtin_amdgcn_s_barrier();

    // ---- phase 1: read B(n2,n3); stage A(T+1) h1
#pragma unroll
    for (int ks = 0; ks < 2; ++ks) {
      const int ct = ks ? ct1 : ct0;
#pragma unroll
      for (int nn = 2; nn < 4; ++nn) bf[ks][nn] = *(const bf16x8*)(bb + nn * 2048 + ct);
    }
    if (T + 1 < 16) stageA(nxt, 1, T + 1);
    __builtin_amdgcn_s_barrier();
    asm volatile("s_waitcnt lgkmcnt(0)");
    __builtin_amdgcn_sched_barrier(0);
    __builtin_amdgcn_s_setprio(1);
#pragma unroll
    for (int ks = 0; ks < 2; ++ks)
#pragma unroll
      for (int mm = 0; mm < 4; ++mm)
#pragma unroll
        for (int nn = 2; nn < 4; ++nn)
          acc[mm][nn] = __builtin_amdgcn_mfma_f32_16x16x32_bf16(af[ks][mm], bf[ks][nn], acc[mm][nn], 0, 0, 0);
    __builtin_amdgcn_s_setprio(0);
    __builtin_amdgcn_s_barrier();

    // ---- phase 2: read A(mh1); stage B(T+2) h0
#pragma unroll
    for (int ks = 0; ks < 2; ++ks) {
      const int ct = ks ? ct1 : ct0;
#pragma unroll
      for (int mm = 0; mm < 4; ++mm) af[ks][mm] = *(const bf16x8*)(ab + 8192 + mm * 2048 + ct);
    }
    if (T + 2 < 16) stageB(cur, 0, T + 2);
    __builtin_amdgcn_s_barrier();
    asm volatile("s_waitcnt lgkmcnt(0)");
    __builtin_amdgcn_sched_barrier(0);
    __builtin_amdgcn_s_setprio(1);
#pragma unroll
    for (int ks = 0; ks < 2; ++ks)
#pragma unroll
      for (int mm = 0; mm < 4; ++mm)
#pragma unroll
        for (int nn = 0; nn < 2; ++nn)
          acc[4 + mm][nn] = __builtin_amdgcn_mfma_f32_16x16x32_bf16(af[ks][mm], bf[ks][nn], acc[4 + mm][nn], 0, 0, 0);
    __builtin_amdgcn_s_setprio(0);
    __builtin_amdgcn_s_barrier();

    // ---- phase 3: no reads; stage B(T+2) h1; counted vmcnt; MFMA quadrant (mh1,nh1)
    if (T + 2 < 16) stageB(cur, 1, T + 2);
    if (T >= 14) asm volatile("s_waitcnt vmcnt(0)");
    else         asm volatile("s_waitcnt vmcnt(4)");
    __builtin_amdgcn_s_barrier();
    __builtin_amdgcn_s_setprio(1);
#pragma unroll
    for (int ks = 0; ks < 2; ++ks)
#pragma unroll
      for (int mm = 0; mm < 4; ++mm)
#pragma unroll
        for (int nn = 2; nn < 4; ++nn)
          acc[4 + mm][nn] = __builtin_amdgcn_mfma_f32_16x16x32_bf16(af[ks][mm], bf[ks][nn], acc[4 + mm][nn], 0, 0, 0);
    __builtin_amdgcn_s_setprio(0);
    __builtin_amdgcn_s_barrier();
  };

  for (int T = 0; T < 16; T += 2) {
    do_tile(T, 0);
    do_tile(T + 1, 1);
  }

  // ---- epilogue: bias (+RoPE for q/k), same mapping as verified 128^2 kernel
  const int n0abs = nt * 256;
  const int grp = n0abs >> 10;  // 0=q 1=k 2=v (tile never straddles: 256 | 1024)
  const int rowb = mt * 256 + wr * 128 + ((l >> 4) << 2);
  const int colb = (n0abs & 1023) + wc * 64 + (l & 15);

  if (grp == 2) {
#pragma unroll
    for (int ni = 0; ni < 4; ++ni) {
      const float bvv = bv[colb + ni * 16];
#pragma unroll
      for (int mi = 0; mi < 8; ++mi)
#pragma unroll
        for (int r = 0; r < 4; ++r) {
          const float v = acc[mi][ni][r] + bvv;
          const size_t idx = (size_t)(rowb + mi * 16 + r) * 1024 + colb + ni * 16;
          ov[idx] = v;
          vb[idx] = (__bf16)v;
        }
    }
  } else {
    const float* bias = grp == 0 ? bq : bk;
    __bf16* Rb = grp == 0 ? qr : kr;
    const float scl = grp == 0 ? SCL2E : 1.0f;
    const float sgn = (l & 1) ? 1.f : -1.f;
#pragma unroll
    for (int ni = 0; ni < 4; ++ni) {
      const int col = colb + ni * 16;
      const float bvv = bias[col];
      const int p = (col & 63) >> 1;
#pragma unroll
      for (int mi = 0; mi < 8; ++mi) {
        const int s_idx = (rowb + mi * 16) >> 2;
        const float cv = fc[s_idx * 32 + p] * scl;
        const float sv = fs[s_idx * 32 + p] * scl * sgn;
#pragma unroll
        for (int r = 0; r < 4; ++r) {
          const float v = acc[mi][ni][r] + bvv;
          if (grp == 1) ok[(size_t)(rowb + mi * 16 + r) * 1024 + col] = v;
          const float part = __shfl_xor(v, 1);
          Rb[(size_t)(rowb + mi * 16 + r) * 1024 + col] = (__bf16)(v * cv + part * sv);
        }
      }
    }
  }
}

// ---------------------------------------------------------------- flash attention v11 (verified, unchanged)
static constexpr int FBUF11 = 16384;

__global__ __launch_bounds__(256, 4) void k_flash11(
    const __bf16* __restrict__ Q, const __bf16* __restrict__ Kr,
    const __bf16* __restrict__ VT, __bf16* __restrict__ O) {
  __shared__ alignas(16) char lds[2 * FBUF11];

  const int t = threadIdx.x, l = t & 63, w = t >> 6;
  const int hf = l >> 5;
  const int q32 = l & 31;
  const int swz = (blockIdx.x & 7) * 128 + (blockIdx.x >> 3);  // XCD-aware
  const int qt = swz & 15;
  const int bh = swz >> 4;
  const int b = bh >> 4, hd = bh & 15;

  const int qrow = qt * 128 + w * 32 + q32;

  bf16x8 qf[4];
#pragma unroll
  for (int kc = 0; kc < 4; ++kc)
    qf[kc] = *(const bf16x8*)(Q + (size_t)(qrow * 4 + b) * DM + hd * 64 + kc * 16 + hf * 8);

  const f32x16 Z = zero16();
  f32x16 acc0 = zero16(), acc1 = zero16();
  float l_run = 0.f;

  const size_t KSTRIDE = (size_t)64 * 4 * DM;
  const size_t VSTRIDE = (size_t)512 * 8;
  const __bf16* kp0 = Kr + (size_t)((t & 31) * 4 + b) * DM + hd * 64 + (t >> 5) * 8;
  const __bf16* kp1 = kp0 + (size_t)32 * 4 * DM;
  const __bf16* vp0 = VT + ((size_t)(bh * 32) * 512 + t) * 8;
  const __bf16* vp1 = vp0 + 256 * 8;

  char* const K0 = lds;
  char* const V0 = lds + 8192;
  char* const K1 = lds + FBUF11;
  char* const V1 = K1 + 8192;

#define STAGE11(Kn, Vn)                         \
  do {                                          \
    gload_lds16(kp0, (Kn) + t * 16);            \
    gload_lds16(kp1, (Kn) + 4096 + t * 16);     \
    gload_lds16(vp0, (Vn) + t * 16);            \
    gload_lds16(vp1, (Vn) + 4096 + t * 16);     \
    kp0 += KSTRIDE; kp1 += KSTRIDE;             \
    vp0 += VSTRIDE; vp1 += VSTRIDE;             \
  } while (0)

  auto PROCESS = [&](const char* Kl, const char* Vl) {
    const bf16x8 kf00 = *(const bf16x8*)(Kl + 0 * 1024 + l * 16);
    const bf16x8 kf10 = *(const bf16x8*)(Kl + 4 * 1024 + l * 16);
    __builtin_amdgcn_s_setprio(1);
    f32x16 s0 = __builtin_amdgcn_mfma_f32_32x32x16_bf16(kf00, qf[0], Z, 0, 0, 0);
    f32x16 s1 = __builtin_amdgcn_mfma_f32_32x32x16_bf16(kf10, qf[0], Z, 0, 0, 0);
#pragma unroll
    for (int kc = 1; kc < 4; ++kc) {
      const bf16x8 kf0 = *(const bf16x8*)(Kl + (0 * 4 + kc) * 1024 + l * 16);
      const bf16x8 kf1 = *(const bf16x8*)(Kl + (1 * 4 + kc) * 1024 + l * 16);
      s0 = __builtin_amdgcn_mfma_f32_32x32x16_bf16(kf0, qf[kc], s0, 0, 0, 0);
      s1 = __builtin_amdgcn_mfma_f32_32x32x16_bf16(kf1, qf[kc], s1, 0, 0, 0);
    }
    __builtin_amdgcn_s_setprio(0);

    f32x16 p0, p1;
#pragma unroll
    for (int r = 0; r < 16; ++r) {
      p0[r] = __builtin_amdgcn_exp2f(s0[r]);
      p1[r] = __builtin_amdgcn_exp2f(s1[r]);
    }

    const f2x8 P0 = __builtin_bit_cast(f2x8, p0);
    const f2x8 P1 = __builtin_bit_cast(f2x8, p1);
    f32x2 a8[8];
#pragma unroll
    for (int j = 0; j < 8; ++j) a8[j] = pk_add(P0.h[j], P1.h[j]);
#pragma unroll
    for (int j = 0; j < 4; ++j) a8[j] = pk_add(a8[j], a8[j + 4]);
    a8[0] = pk_add(a8[0], a8[2]);
    a8[1] = pk_add(a8[1], a8[3]);
    a8[0] = pk_add(a8[0], a8[1]);
    float rs = a8[0][0] + a8[0][1];
    {
      float tmp = rs;
      asm("v_permlane32_swap_b32 %0, %1" : "+v"(rs), "+v"(tmp));
      rs = rs + tmp;
    }
    l_run += rs;

    unsigned pkw[16];
#pragma unroll
    for (int j = 0; j < 8; ++j) {
      pkw[j]     = pack_bf16(P0.h[j][0], P0.h[j][1]);
      pkw[8 + j] = pack_bf16(P1.h[j][0], P1.h[j][1]);
    }

#pragma unroll
    for (int c = 0; c < 2; ++c)
#pragma unroll
      for (int jc2 = 0; jc2 < 2; ++jc2) {
        unsigned w0 = pkw[c * 8 + 4 * jc2 + 0], w2 = pkw[c * 8 + 4 * jc2 + 2];
        unsigned w1 = pkw[c * 8 + 4 * jc2 + 1], w3 = pkw[c * 8 + 4 * jc2 + 3];
        asm("v_permlane32_swap_b32 %0, %1" : "+v"(w0), "+v"(w2));
        asm("v_permlane32_swap_b32 %0, %1" : "+v"(w1), "+v"(w3));
        const u32x4 pw = { w0, w1, w2, w3 };
        const bf16x8 pf = __builtin_bit_cast(bf16x8, pw);
        const int jc = c * 2 + jc2;
        const bf16x8 vf0 = *(const bf16x8*)(Vl + (jc * 2 + 0) * 1024 + l * 16);
        const bf16x8 vf1 = *(const bf16x8*)(Vl + (jc * 2 + 1) * 1024 + l * 16);
        __builtin_amdgcn_s_setprio(1);
        acc0 = __builtin_amdgcn_mfma_f32_32x32x16_bf16(vf0, pf, acc0, 0, 0, 0);
        acc1 = __builtin_amdgcn_mfma_f32_32x32x16_bf16(vf1, pf, acc1, 0, 0, 0);
        __builtin_amdgcn_s_setprio(0);
      }
  };

  STAGE11(K0, V0);

  for (int kt = 0; kt < QLEN / 64; kt += 2) {
    __syncthreads();
    STAGE11(K1, V1);
    PROCESS(K0, V0);
    __syncthreads();
    if (kt + 2 < QLEN / 64) STAGE11(K0, V0);
    PROCESS(K1, V1);
  }
#undef STAGE11

  const float inv = 1.0f / l_run;
#pragma unroll
  for (int g = 0; g < 4; ++g) {
    {
      const int d0 = 8 * g + 4 * hf;
      bf16x4 o4 = { (__bf16)(acc0[4 * g + 0] * inv), (__bf16)(acc0[4 * g + 1] * inv),
                    (__bf16)(acc0[4 * g + 2] * inv), (__bf16)(acc0[4 * g + 3] * inv) };
      *(bf16x4*)&O[(size_t)(qrow * 4 + b) * DM + hd * 64 + d0] = o4;
    }
    {
      const int d0 = 32 + 8 * g + 4 * hf;
      bf16x4 o4 = { (__bf16)(acc1[4 * g + 0] * inv), (__bf16)(acc1[4 * g + 1] * inv),
                    (__bf16)(acc1[4 * g + 2] * inv), (__bf16)(acc1[4 * g + 3] * inv) };
      *(bf16x4*)&O[(size_t)(qrow * 4 + b) * DM + hd * 64 + d0] = o4;
    }
  }
}

// ---------------------------------------------------------------- launch
extern "C" void kernel_launch(void* const* d_in, const int* in_sizes, int n_in,
                              void* d_out, int out_size, void* d_ws, size_t ws_size,
                              hipStream_t stream) {
  const float* x    = (const float*)d_in[0];
  const float* fcos = (const float*)d_in[1];
  const float* fsin = (const float*)d_in[2];
  const float* Wq   = (const float*)d_in[3];
  const float* bq   = (const float*)d_in[4];
  const float* Wk   = (const float*)d_in[5];
  const float* bk   = (const float*)d_in[6];
  const float* Wv   = (const float*)d_in[7];
  const float* bv   = (const float*)d_in[8];
  const float* Wo   = (const float*)d_in[9];
  const float* bo   = (const float*)d_in[10];

  float* out_o = (float*)d_out;
  float* out_k = out_o + OSZ;
  float* out_v = out_o + 2 * OSZ;

  char* ws = (char*)d_ws;
  __bf16* xb  = (__bf16*)(ws);              // 16MB; reused as VT2 after QKV GEMM
  __bf16* VT  = (__bf16*)(ws);
  __bf16* wqt = (__bf16*)(ws + 16777216);   // wqt|wkt|wvt|wot contiguous
  __bf16* wot = (__bf16*)(ws + 23068672);
  __bf16* qr  = (__bf16*)(ws + 25165824);
  __bf16* kr  = (__bf16*)(ws + 41943040);
  __bf16* vb  = (__bf16*)(ws + 58720256);
  __bf16* ao  = (__bf16*)(ws + 75497472);

  k_prep<<<3072, 256, 0, stream>>>(x, xb, Wq, Wk, Wv, Wo, wqt);

  k_gemm_qkv8<<<384, 512, 0, stream>>>(xb, wqt, bq, bk, bv, fcos, fsin,
                                       out_k, out_v, qr, kr, vb);

  k_vtrans<<<1024, 256, 0, stream>>>(vb, VT);

  k_flash11<<<1024, 256, 0, stream>>>(qr, kr, VT, ao);

  k_gemm<<<512, 256, 0, stream>>>(ao, wot, bo, out_o);
}

// Round 13
// 234.116 us; speedup vs baseline: 1.0038x; 1.0038x over previous
//
#include <hip/hip_runtime.h>

typedef __attribute__((ext_vector_type(2))) float f32x2;
typedef __attribute__((ext_vector_type(4))) float f32x4;
typedef __attribute__((ext_vector_type(16))) float f32x16;
typedef __attribute__((ext_vector_type(8))) __bf16 bf16x8;
typedef __attribute__((ext_vector_type(4))) __bf16 bf16x4;
typedef __attribute__((ext_vector_type(2))) __bf16 bf16x2;
typedef __attribute__((ext_vector_type(4))) unsigned int u32x4;

#define DEVI __device__ __forceinline__

static constexpr int QLEN = 2048, BSZ = 4, DM = 1024, NH = 16, DH = 64;
static constexpr int MROWS = QLEN * BSZ;       // 8192
static constexpr long OSZ  = (long)MROWS * DM; // 8388608 elements per output tensor
static constexpr float SCL2E = 0.125f * 1.4426950408889634f; // SCALE * log2(e), folded into Q

DEVI void gload_lds16(const void* g, void* l) {
  __builtin_amdgcn_global_load_lds(
      (__attribute__((address_space(1))) void*)(size_t)g,
      (__attribute__((address_space(3))) void*)l, 16, 0, 0);
}

DEVI f32x16 zero16() {
  f32x16 v;
#pragma unroll
  for (int i = 0; i < 16; ++i) v[i] = 0.f;
  return v;
}

DEVI unsigned pack_bf16(float lo, float hi) {
  bf16x2 v = { (__bf16)lo, (__bf16)hi };
  return __builtin_bit_cast(unsigned, v);
}

struct f2x8 { f32x2 h[8]; };

DEVI f32x2 pk_add(f32x2 a, f32x2 b) {
  f32x2 d;
  asm("v_pk_add_f32 %0, %1, %2" : "=v"(d) : "v"(a), "v"(b));
  return d;
}

// ------------------------------------------------- prep: x fp32->bf16 + 4x wtrans
__global__ void k_prep(const float* __restrict__ x, __bf16* __restrict__ xb,
                       const float* __restrict__ W0, const float* __restrict__ W1,
                       const float* __restrict__ W2, const float* __restrict__ W3,
                       __bf16* __restrict__ WtAll) {
  __shared__ float tile[64][65];
  const int t = threadIdx.x;
  if (blockIdx.x < 1024) {
    const int g = blockIdx.x >> 8;     // 0..3
    const float* W = g == 0 ? W0 : (g == 1 ? W1 : (g == 2 ? W2 : W3));
    __bf16* Wt = WtAll + (size_t)g * DM * DM;
    const int bid = blockIdx.x & 255;
    const int tk = bid >> 4;
    const int tn = bid & 15;
    const int r = t >> 4;
    const int c4 = (t & 15) << 2;
#pragma unroll
    for (int i = 0; i < 4; ++i) {
      const float4 v = *(const float4*)&W[(size_t)(tk * 64 + r + i * 16) * DM + tn * 64 + c4];
      tile[r + i * 16][c4 + 0] = v.x;
      tile[r + i * 16][c4 + 1] = v.y;
      tile[r + i * 16][c4 + 2] = v.z;
      tile[r + i * 16][c4 + 3] = v.w;
    }
    __syncthreads();
#pragma unroll
    for (int i = 0; i < 4; ++i) {
      const int n = r + i * 16;
      bf16x4 o = { (__bf16)tile[c4 + 0][n], (__bf16)tile[c4 + 1][n],
                   (__bf16)tile[c4 + 2][n], (__bf16)tile[c4 + 3][n] };
      *(bf16x4*)&Wt[(size_t)(tn * 64 + n) * DM + tk * 64 + c4] = o;
    }
  } else {
    const int n4 = (int)(OSZ / 4);
    int i = (blockIdx.x - 1024) * 256 + t;
    for (; i < n4; i += 2048 * 256) {
      const float4 v = ((const float4*)x)[i];
      bf16x4 o = { (__bf16)v.x, (__bf16)v.y, (__bf16)v.z, (__bf16)v.w };
      ((bf16x4*)xb)[i] = o;
    }
  }
}

// ------------------------------------------------- V bf16 -> slab-tiled VT2
__global__ __launch_bounds__(256, 4) void k_vtrans(const __bf16* __restrict__ vb,
                                                   __bf16* __restrict__ VT) {
  __shared__ __bf16 tile[128 * 72];   // row stride 72 bf16 (36 dw)
  const int t = threadIdx.x;
  const int bh = blockIdx.x >> 4;
  const int s0 = (blockIdx.x & 15) * 128;
  const int b = bh >> 4, h = bh & 15;

  {
    const int r = t >> 1, hh = t & 1;
    const __bf16* src = vb + (size_t)((s0 + r) * 4 + b) * DM + h * 64 + hh * 32;
    __bf16* dst = tile + r * 72 + hh * 32;
#pragma unroll
    for (int k = 0; k < 4; ++k)
      *(bf16x8*)(dst + k * 8) = *(const bf16x8*)(src + k * 8);
  }
  __syncthreads();

  const int l = t & 63;
  const int w = t >> 6;
  const int hf = l >> 5;
#pragma unroll
  for (int gi = 0; gi < 4; ++gi) {
    const int idx = w * 4 + gi;
    const int ktl = idx >> 3;
    const int fi = idx & 7;
    const int jc = fi >> 1, dh = fi & 1;
    const int d = dh * 32 + (l & 31);
    const int j8 = ktl * 64 + jc * 16 + hf * 8;
    bf16x8 pk;
#pragma unroll
    for (int jj = 0; jj < 8; ++jj) pk[jj] = tile[(j8 + jj) * 72 + d];
    const int kt_g = (blockIdx.x & 15) * 2 + ktl;
    *(bf16x8*)&VT[(size_t)(((bh * 32 + kt_g) * 8 + fi) * 64 + l) * 8] = pk;
  }
}

// ---------------------------------------------------------------- GEMM core (128^2, m97 structure)
DEVI void gemm_tile_core(const __bf16* __restrict__ A, const __bf16* __restrict__ Bt,
                         char* Alds, char* Blds, int m0, int n0, int t,
                         f32x4 (&acc)[4][4]) {
  constexpr int K = 1024;
  const int l = t & 63;
  const int w = t >> 6;
  const int wr = w >> 1, wc = w & 1;

  int a_addr[2][4], b_addr[2][4];
#pragma unroll
  for (int s = 0; s < 2; ++s)
#pragma unroll
    for (int f = 0; f < 4; ++f) {
      const int ca = s * 64 + ((l >> 4) << 4);
      const int ra = wr * 64 + f * 16 + (l & 15);
      a_addr[s][f] = ra * 128 + (ca ^ ((ra & 7) << 4));
      const int rb = wc * 64 + f * 16 + (l & 15);
      b_addr[s][f] = rb * 128 + (ca ^ ((rb & 7) << 4));
    }

  int g_row[4], g_col[4];
#pragma unroll
  for (int i = 0; i < 4; ++i) {
    const int g = i * 256 + t;
    g_row[i] = g >> 3;
    g_col[i] = ((g & 7) ^ (g_row[i] & 7)) * 8;
  }

  for (int kt = 0; kt < K / 64; ++kt) {
#pragma unroll
    for (int i = 0; i < 4; ++i) {
      gload_lds16(A + (size_t)(m0 + g_row[i]) * K + kt * 64 + g_col[i],
                  Alds + (size_t)(i * 256 + t) * 16);
      gload_lds16(Bt + (size_t)(n0 + g_row[i]) * K + kt * 64 + g_col[i],
                  Blds + (size_t)(i * 256 + t) * 16);
    }
    __syncthreads();
#pragma unroll
    for (int s = 0; s < 2; ++s) {
      bf16x8 af[4], bfr[4];
#pragma unroll
      for (int f = 0; f < 4; ++f) {
        af[f]  = *(const bf16x8*)(Alds + a_addr[s][f]);
        bfr[f] = *(const bf16x8*)(Blds + b_addr[s][f]);
      }
      __builtin_amdgcn_s_setprio(1);
#pragma unroll
      for (int mi = 0; mi < 4; ++mi)
#pragma unroll
        for (int ni = 0; ni < 4; ++ni)
          acc[mi][ni] = __builtin_amdgcn_mfma_f32_16x16x32_bf16(af[mi], bfr[ni], acc[mi][ni], 0, 0, 0);
      __builtin_amdgcn_s_setprio(0);
    }
    __syncthreads();
  }
}

// Final GEMM: N=1024 single fp32 output (unchanged, verified)
__global__ __launch_bounds__(256, 3) void k_gemm(
    const __bf16* __restrict__ A, const __bf16* __restrict__ Bt,
    const float* __restrict__ bias, float* __restrict__ Cf) {
  __shared__ alignas(16) char lds[32768];
  const int t = threadIdx.x;
  const int l = t & 63;
  const int w = t >> 6;
  const int n0 = (blockIdx.x & 7) * 128;
  const int m0 = (blockIdx.x >> 3) * 128;
  const int wr = w >> 1, wc = w & 1;

  f32x4 acc[4][4];
#pragma unroll
  for (int i = 0; i < 4; ++i)
#pragma unroll
    for (int j = 0; j < 4; ++j) acc[i][j] = (f32x4){0.f, 0.f, 0.f, 0.f};

  gemm_tile_core(A, Bt, lds, lds + 16384, m0, n0, t, acc);

  const int rowb = m0 + wr * 64 + ((l >> 4) << 2);
  const int colb = n0 + wc * 64 + (l & 15);
#pragma unroll
  for (int ni = 0; ni < 4; ++ni) {
    const float bv = bias[colb + ni * 16];
#pragma unroll
    for (int mi = 0; mi < 4; ++mi)
#pragma unroll
      for (int r = 0; r < 4; ++r)
        Cf[(size_t)(rowb + mi * 16 + r) * 1024 + colb + ni * 16] = acc[mi][ni][r] + bv;
  }
}

// ---------------------------------------------------------------- QKV GEMM, 8-phase 256^2
// Identical schedule to round 12 (correctness-validated); launch_bounds(512,1)
// so VGPR cap is 512 (needs ~220; round-12's (512,2) capped at 128 -> 145MB spill).
// 128KB LDS forces 1 block/CU regardless; the counted-vmcnt pipeline provides
// the latency hiding, not TLP.
__global__ __launch_bounds__(512, 1) void k_gemm_qkv8(
    const __bf16* __restrict__ A, const __bf16* __restrict__ Bt,
    const float* __restrict__ bq, const float* __restrict__ bk, const float* __restrict__ bv,
    const float* __restrict__ fc, const float* __restrict__ fs,
    float* __restrict__ ok, float* __restrict__ ov,
    __bf16* __restrict__ qr, __bf16* __restrict__ kr, __bf16* __restrict__ vb) {
  __shared__ alignas(16) char lds[131072];
  const int t = threadIdx.x;          // 0..511
  const int l = t & 63;
  const int wid = t >> 6;             // 0..7
  const int wr = wid >> 2;            // 0..1  (M half)
  const int wc = wid & 3;             // 0..3  (N quarter)

  const int swz = (blockIdx.x & 7) * 48 + (blockIdx.x >> 3);  // bijective, 384%8==0
  const int mt = swz & 31;            // 0..31
  const int nt = swz >> 5;            // 0..11

  size_t aoff[2], boff[2];
#pragma unroll
  for (int i = 0; i < 2; ++i) {
    const int g = i * 512 + t;
    const int row = g >> 3;                    // 0..127
    const int c16 = (g & 7) ^ (row & 7);
    aoff[i] = (size_t)(mt * 256 + row) * 1024 + c16 * 8;
    boff[i] = (size_t)(nt * 256 + row) * 1024 + c16 * 8;
  }

  const int rowbyte = (l & 15) * 128;
  const int ct0 = (((l >> 4) << 4)) ^ ((l & 7) << 4);
  const int ct1 = (64 + ((l >> 4) << 4)) ^ ((l & 7) << 4);

  f32x4 acc[8][4];
#pragma unroll
  for (int i = 0; i < 8; ++i)
#pragma unroll
    for (int j = 0; j < 4; ++j) acc[i][j] = (f32x4){0.f, 0.f, 0.f, 0.f};

  bf16x8 af[2][4], bf[2][4];

  auto stageA = [&](int d, int h, int kt) {
#pragma unroll
    for (int i = 0; i < 2; ++i)
      gload_lds16(A + aoff[i] + (size_t)h * 131072 + kt * 64,
                  lds + d * 65536 + h * 16384 + (size_t)(i * 512 + t) * 16);
  };
  auto stageB = [&](int d, int h, int kt) {
#pragma unroll
    for (int i = 0; i < 2; ++i)
      gload_lds16(Bt + boff[i] + (size_t)h * 131072 + kt * 64,
                  lds + d * 65536 + 32768 + h * 16384 + (size_t)(i * 512 + t) * 16);
  };

  // ---- prologue: A(t0), B(t0), B(t1); ensure t0 complete (vmcnt(4) = allow B(t1))
  stageA(0, 0, 0); stageA(0, 1, 0);
  stageB(0, 0, 0); stageB(0, 1, 0);
  stageB(1, 0, 1); stageB(1, 1, 1);
  asm volatile("s_waitcnt vmcnt(4)");
  __builtin_amdgcn_s_barrier();

  auto do_tile = [&](int T, int cur) {
    const char* ab = lds + cur * 65536 + wr * 16384 + rowbyte;
    const char* bb = lds + cur * 65536 + 32768 + (wc >> 1) * 16384 + (wc & 1) * 8192 + rowbyte;
    const int nxt = cur ^ 1;

    // ---- phase 0: read A(mh0) + B(n0,n1); stage A(T+1) h0
#pragma unroll
    for (int ks = 0; ks < 2; ++ks) {
      const int ct = ks ? ct1 : ct0;
#pragma unroll
      for (int mm = 0; mm < 4; ++mm) af[ks][mm] = *(const bf16x8*)(ab + mm * 2048 + ct);
#pragma unroll
      for (int nn = 0; nn < 2; ++nn) bf[ks][nn] = *(const bf16x8*)(bb + nn * 2048 + ct);
    }
    if (T + 1 < 16) stageA(nxt, 0, T + 1);
    __builtin_amdgcn_s_barrier();
    asm volatile("s_waitcnt lgkmcnt(0)");
    __builtin_amdgcn_sched_barrier(0);
    __builtin_amdgcn_s_setprio(1);
#pragma unroll
    for (int ks = 0; ks < 2; ++ks)
#pragma unroll
      for (int mm = 0; mm < 4; ++mm)
#pragma unroll
        for (int nn = 0; nn < 2; ++nn)
          acc[mm][nn] = __builtin_amdgcn_mfma_f32_16x16x32_bf16(af[ks][mm], bf[ks][nn], acc[mm][nn], 0, 0, 0);
    __builtin_amdgcn_s_setprio(0);
    __builtin_amdgcn_s_barrier();

    // ---- phase 1: read B(n2,n3); stage A(T+1) h1
#pragma unroll
    for (int ks = 0; ks < 2; ++ks) {
      const int ct = ks ? ct1 : ct0;
#pragma unroll
      for (int nn = 2; nn < 4; ++nn) bf[ks][nn] = *(const bf16x8*)(bb + nn * 2048 + ct);
    }
    if (T + 1 < 16) stageA(nxt, 1, T + 1);
    __builtin_amdgcn_s_barrier();
    asm volatile("s_waitcnt lgkmcnt(0)");
    __builtin_amdgcn_sched_barrier(0);
    __builtin_amdgcn_s_setprio(1);
#pragma unroll
    for (int ks = 0; ks < 2; ++ks)
#pragma unroll
      for (int mm = 0; mm < 4; ++mm)
#pragma unroll
        for (int nn = 2; nn < 4; ++nn)
          acc[mm][nn] = __builtin_amdgcn_mfma_f32_16x16x32_bf16(af[ks][mm], bf[ks][nn], acc[mm][nn], 0, 0, 0);
    __builtin_amdgcn_s_setprio(0);
    __builtin_amdgcn_s_barrier();

    // ---- phase 2: read A(mh1); stage B(T+2) h0
#pragma unroll
    for (int ks = 0; ks < 2; ++ks) {
      const int ct = ks ? ct1 : ct0;
#pragma unroll
      for (int mm = 0; mm < 4; ++mm) af[ks][mm] = *(const bf16x8*)(ab + 8192 + mm * 2048 + ct);
    }
    if (T + 2 < 16) stageB(cur, 0, T + 2);
    __builtin_amdgcn_s_barrier();
    asm volatile("s_waitcnt lgkmcnt(0)");
    __builtin_amdgcn_sched_barrier(0);
    __builtin_amdgcn_s_setprio(1);
#pragma unroll
    for (int ks = 0; ks < 2; ++ks)
#pragma unroll
      for (int mm = 0; mm < 4; ++mm)
#pragma unroll
        for (int nn = 0; nn < 2; ++nn)
          acc[4 + mm][nn] = __builtin_amdgcn_mfma_f32_16x16x32_bf16(af[ks][mm], bf[ks][nn], acc[4 + mm][nn], 0, 0, 0);
    __builtin_amdgcn_s_setprio(0);
    __builtin_amdgcn_s_barrier();

    // ---- phase 3: no reads; stage B(T+2) h1; counted vmcnt; MFMA quadrant (mh1,nh1)
    if (T + 2 < 16) stageB(cur, 1, T + 2);
    if (T >= 14) asm volatile("s_waitcnt vmcnt(0)");
    else         asm volatile("s_waitcnt vmcnt(4)");
    __builtin_amdgcn_s_barrier();
    __builtin_amdgcn_s_setprio(1);
#pragma unroll
    for (int ks = 0; ks < 2; ++ks)
#pragma unroll
      for (int mm = 0; mm < 4; ++mm)
#pragma unroll
        for (int nn = 2; nn < 4; ++nn)
          acc[4 + mm][nn] = __builtin_amdgcn_mfma_f32_16x16x32_bf16(af[ks][mm], bf[ks][nn], acc[4 + mm][nn], 0, 0, 0);
    __builtin_amdgcn_s_setprio(0);
    __builtin_amdgcn_s_barrier();
  };

  for (int T = 0; T < 16; T += 2) {
    do_tile(T, 0);
    do_tile(T + 1, 1);
  }

  // ---- epilogue: bias (+RoPE for q/k)
  const int n0abs = nt * 256;
  const int grp = n0abs >> 10;  // 0=q 1=k 2=v (tile never straddles: 256 | 1024)
  const int rowb = mt * 256 + wr * 128 + ((l >> 4) << 2);
  const int colb = (n0abs & 1023) + wc * 64 + (l & 15);

  if (grp == 2) {
#pragma unroll
    for (int ni = 0; ni < 4; ++ni) {
      const float bvv = bv[colb + ni * 16];
#pragma unroll
      for (int mi = 0; mi < 8; ++mi)
#pragma unroll
        for (int r = 0; r < 4; ++r) {
          const float v = acc[mi][ni][r] + bvv;
          const size_t idx = (size_t)(rowb + mi * 16 + r) * 1024 + colb + ni * 16;
          ov[idx] = v;
          vb[idx] = (__bf16)v;
        }
    }
  } else {
    const float* bias = grp == 0 ? bq : bk;
    __bf16* Rb = grp == 0 ? qr : kr;
    const float scl = grp == 0 ? SCL2E : 1.0f;
    const float sgn = (l & 1) ? 1.f : -1.f;
#pragma unroll
    for (int ni = 0; ni < 4; ++ni) {
      const int col = colb + ni * 16;
      const float bvv = bias[col];
      const int p = (col & 63) >> 1;
#pragma unroll
      for (int mi = 0; mi < 8; ++mi) {
        const int s_idx = (rowb + mi * 16) >> 2;
        const float cv = fc[s_idx * 32 + p] * scl;
        const float sv = fs[s_idx * 32 + p] * scl * sgn;
#pragma unroll
        for (int r = 0; r < 4; ++r) {
          const float v = acc[mi][ni][r] + bvv;
          if (grp == 1) ok[(size_t)(rowb + mi * 16 + r) * 1024 + col] = v;
          const float part = __shfl_xor(v, 1);
          Rb[(size_t)(rowb + mi * 16 + r) * 1024 + col] = (__bf16)(v * cv + part * sv);
        }
      }
    }
  }
}

// ---------------------------------------------------------------- flash attention v11 (verified, unchanged)
static constexpr int FBUF11 = 16384;

__global__ __launch_bounds__(256, 4) void k_flash11(
    const __bf16* __restrict__ Q, const __bf16* __restrict__ Kr,
    const __bf16* __restrict__ VT, __bf16* __restrict__ O) {
  __shared__ alignas(16) char lds[2 * FBUF11];

  const int t = threadIdx.x, l = t & 63, w = t >> 6;
  const int hf = l >> 5;
  const int q32 = l & 31;
  const int swz = (blockIdx.x & 7) * 128 + (blockIdx.x >> 3);  // XCD-aware
  const int qt = swz & 15;
  const int bh = swz >> 4;
  const int b = bh >> 4, hd = bh & 15;

  const int qrow = qt * 128 + w * 32 + q32;

  bf16x8 qf[4];
#pragma unroll
  for (int kc = 0; kc < 4; ++kc)
    qf[kc] = *(const bf16x8*)(Q + (size_t)(qrow * 4 + b) * DM + hd * 64 + kc * 16 + hf * 8);

  const f32x16 Z = zero16();
  f32x16 acc0 = zero16(), acc1 = zero16();
  float l_run = 0.f;

  const size_t KSTRIDE = (size_t)64 * 4 * DM;
  const size_t VSTRIDE = (size_t)512 * 8;
  const __bf16* kp0 = Kr + (size_t)((t & 31) * 4 + b) * DM + hd * 64 + (t >> 5) * 8;
  const __bf16* kp1 = kp0 + (size_t)32 * 4 * DM;
  const __bf16* vp0 = VT + ((size_t)(bh * 32) * 512 + t) * 8;
  const __bf16* vp1 = vp0 + 256 * 8;

  char* const K0 = lds;
  char* const V0 = lds + 8192;
  char* const K1 = lds + FBUF11;
  char* const V1 = K1 + 8192;

#define STAGE11(Kn, Vn)                         \
  do {                                          \
    gload_lds16(kp0, (Kn) + t * 16);            \
    gload_lds16(kp1, (Kn) + 4096 + t * 16);     \
    gload_lds16(vp0, (Vn) + t * 16);            \
    gload_lds16(vp1, (Vn) + 4096 + t * 16);     \
    kp0 += KSTRIDE; kp1 += KSTRIDE;             \
    vp0 += VSTRIDE; vp1 += VSTRIDE;             \
  } while (0)

  auto PROCESS = [&](const char* Kl, const char* Vl) {
    const bf16x8 kf00 = *(const bf16x8*)(Kl + 0 * 1024 + l * 16);
    const bf16x8 kf10 = *(const bf16x8*)(Kl + 4 * 1024 + l * 16);
    __builtin_amdgcn_s_setprio(1);
    f32x16 s0 = __builtin_amdgcn_mfma_f32_32x32x16_bf16(kf00, qf[0], Z, 0, 0, 0);
    f32x16 s1 = __builtin_amdgcn_mfma_f32_32x32x16_bf16(kf10, qf[0], Z, 0, 0, 0);
#pragma unroll
    for (int kc = 1; kc < 4; ++kc) {
      const bf16x8 kf0 = *(const bf16x8*)(Kl + (0 * 4 + kc) * 1024 + l * 16);
      const bf16x8 kf1 = *(const bf16x8*)(Kl + (1 * 4 + kc) * 1024 + l * 16);
      s0 = __builtin_amdgcn_mfma_f32_32x32x16_bf16(kf0, qf[kc], s0, 0, 0, 0);
      s1 = __builtin_amdgcn_mfma_f32_32x32x16_bf16(kf1, qf[kc], s1, 0, 0, 0);
    }
    __builtin_amdgcn_s_setprio(0);

    f32x16 p0, p1;
#pragma unroll
    for (int r = 0; r < 16; ++r) {
      p0[r] = __builtin_amdgcn_exp2f(s0[r]);
      p1[r] = __builtin_amdgcn_exp2f(s1[r]);
    }

    const f2x8 P0 = __builtin_bit_cast(f2x8, p0);
    const f2x8 P1 = __builtin_bit_cast(f2x8, p1);
    f32x2 a8[8];
#pragma unroll
    for (int j = 0; j < 8; ++j) a8[j] = pk_add(P0.h[j], P1.h[j]);
#pragma unroll
    for (int j = 0; j < 4; ++j) a8[j] = pk_add(a8[j], a8[j + 4]);
    a8[0] = pk_add(a8[0], a8[2]);
    a8[1] = pk_add(a8[1], a8[3]);
    a8[0] = pk_add(a8[0], a8[1]);
    float rs = a8[0][0] + a8[0][1];
    {
      float tmp = rs;
      asm("v_permlane32_swap_b32 %0, %1" : "+v"(rs), "+v"(tmp));
      rs = rs + tmp;
    }
    l_run += rs;

    unsigned pkw[16];
#pragma unroll
    for (int j = 0; j < 8; ++j) {
      pkw[j]     = pack_bf16(P0.h[j][0], P0.h[j][1]);
      pkw[8 + j] = pack_bf16(P1.h[j][0], P1.h[j][1]);
    }

#pragma unroll
    for (int c = 0; c < 2; ++c)
#pragma unroll
      for (int jc2 = 0; jc2 < 2; ++jc2) {
        unsigned w0 = pkw[c * 8 + 4 * jc2 + 0], w2 = pkw[c * 8 + 4 * jc2 + 2];
        unsigned w1 = pkw[c * 8 + 4 * jc2 + 1], w3 = pkw[c * 8 + 4 * jc2 + 3];
        asm("v_permlane32_swap_b32 %0, %1" : "+v"(w0), "+v"(w2));
        asm("v_permlane32_swap_b32 %0, %1" : "+v"(w1), "+v"(w3));
        const u32x4 pw = { w0, w1, w2, w3 };
        const bf16x8 pf = __builtin_bit_cast(bf16x8, pw);
        const int jc = c * 2 + jc2;
        const bf16x8 vf0 = *(const bf16x8*)(Vl + (jc * 2 + 0) * 1024 + l * 16);
        const bf16x8 vf1 = *(const bf16x8*)(Vl + (jc * 2 + 1) * 1024 + l * 16);
        __builtin_amdgcn_s_setprio(1);
        acc0 = __builtin_amdgcn_mfma_f32_32x32x16_bf16(vf0, pf, acc0, 0, 0, 0);
        acc1 = __builtin_amdgcn_mfma_f32_32x32x16_bf16(vf1, pf, acc1, 0, 0, 0);
        __builtin_amdgcn_s_setprio(0);
      }
  };

  STAGE11(K0, V0);

  for (int kt = 0; kt < QLEN / 64; kt += 2) {
    __syncthreads();
    STAGE11(K1, V1);
    PROCESS(K0, V0);
    __syncthreads();
    if (kt + 2 < QLEN / 64) STAGE11(K0, V0);
    PROCESS(K1, V1);
  }
#undef STAGE11

  const float inv = 1.0f / l_run;
#pragma unroll
  for (int g = 0; g < 4; ++g) {
    {
      const int d0 = 8 * g + 4 * hf;
      bf16x4 o4 = { (__bf16)(acc0[4 * g + 0] * inv), (__bf16)(acc0[4 * g + 1] * inv),
                    (__bf16)(acc0[4 * g + 2] * inv), (__bf16)(acc0[4 * g + 3] * inv) };
      *(bf16x4*)&O[(size_t)(qrow * 4 + b) * DM + hd * 64 + d0] = o4;
    }
    {
      const int d0 = 32 + 8 * g + 4 * hf;
      bf16x4 o4 = { (__bf16)(acc1[4 * g + 0] * inv), (__bf16)(acc1[4 * g + 1] * inv),
                    (__bf16)(acc1[4 * g + 2] * inv), (__bf16)(acc1[4 * g + 3] * inv) };
      *(bf16x4*)&O[(size_t)(qrow * 4 + b) * DM + hd * 64 + d0] = o4;
    }
  }
}

// ---------------------------------------------------------------- launch
extern "C" void kernel_launch(void* const* d_in, const int* in_sizes, int n_in,
                              void* d_out, int out_size, void* d_ws, size_t ws_size,
                              hipStream_t stream) {
  const float* x    = (const float*)d_in[0];
  const float* fcos = (const float*)d_in[1];
  const float* fsin = (const float*)d_in[2];
  const float* Wq   = (const float*)d_in[3];
  const float* bq   = (const float*)d_in[4];
  const float* Wk   = (const float*)d_in[5];
  const float* bk   = (const float*)d_in[6];
  const float* Wv   = (const float*)d_in[7];
  const float* bv   = (const float*)d_in[8];
  const float* Wo   = (const float*)d_in[9];
  const float* bo   = (const float*)d_in[10];

  float* out_o = (float*)d_out;
  float* out_k = out_o + OSZ;
  float* out_v = out_o + 2 * OSZ;

  char* ws = (char*)d_ws;
  __bf16* xb  = (__bf16*)(ws);              // 16MB; reused as VT2 after QKV GEMM
  __bf16* VT  = (__bf16*)(ws);
  __bf16* wqt = (__bf16*)(ws + 16777216);   // wqt|wkt|wvt|wot contiguous
  __bf16* wot = (__bf16*)(ws + 23068672);
  __bf16* qr  = (__bf16*)(ws + 25165824);
  __bf16* kr  = (__bf16*)(ws + 41943040);
  __bf16* vb  = (__bf16*)(ws + 58720256);
  __bf16* ao  = (__bf16*)(ws + 75497472);

  k_prep<<<3072, 256, 0, stream>>>(x, xb, Wq, Wk, Wv, Wo, wqt);

  k_gemm_qkv8<<<384, 512, 0, stream>>>(xb, wqt, bq, bk, bv, fcos, fsin,
                                       out_k, out_v, qr, kr, vb);

  k_vtrans<<<1024, 256, 0, stream>>>(vb, VT);

  k_flash11<<<1024, 256, 0, stream>>>(qr, kr, VT, ao);

  k_gemm<<<512, 256, 0, stream>>>(ao, wot, bo, out_o);
}

// Round 14
// 195.767 us; speedup vs baseline: 1.2004x; 1.1959x over previous
//
#include <hip/hip_runtime.h>

typedef __attribute__((ext_vector_type(2))) float f32x2;
typedef __attribute__((ext_vector_type(4))) float f32x4;
typedef __attribute__((ext_vector_type(16))) float f32x16;
typedef __attribute__((ext_vector_type(8))) __bf16 bf16x8;
typedef __attribute__((ext_vector_type(4))) __bf16 bf16x4;
typedef __attribute__((ext_vector_type(2))) __bf16 bf16x2;
typedef __attribute__((ext_vector_type(4))) unsigned int u32x4;

#define DEVI __device__ __forceinline__

static constexpr int QLEN = 2048, BSZ = 4, DM = 1024, NH = 16, DH = 64;
static constexpr int MROWS = QLEN * BSZ;       // 8192
static constexpr long OSZ  = (long)MROWS * DM; // 8388608 elements per output tensor
static constexpr float SCL2E = 0.125f * 1.4426950408889634f; // SCALE * log2(e), folded into Q

DEVI void gload_lds16(const void* g, void* l) {
  __builtin_amdgcn_global_load_lds(
      (__attribute__((address_space(1))) void*)(size_t)g,
      (__attribute__((address_space(3))) void*)l, 16, 0, 0);
}

DEVI f32x16 zero16() {
  f32x16 v;
#pragma unroll
  for (int i = 0; i < 16; ++i) v[i] = 0.f;
  return v;
}

DEVI unsigned pack_bf16(float lo, float hi) {
  bf16x2 v = { (__bf16)lo, (__bf16)hi };
  return __builtin_bit_cast(unsigned, v);
}

struct f2x8 { f32x2 h[8]; };

DEVI f32x2 pk_add(f32x2 a, f32x2 b) {
  f32x2 d;
  asm("v_pk_add_f32 %0, %1, %2" : "=v"(d) : "v"(a), "v"(b));
  return d;
}

// ------------------------------------------------- prep: x fp32->bf16 + 4x wtrans
__global__ void k_prep(const float* __restrict__ x, __bf16* __restrict__ xb,
                       const float* __restrict__ W0, const float* __restrict__ W1,
                       const float* __restrict__ W2, const float* __restrict__ W3,
                       __bf16* __restrict__ WtAll) {
  __shared__ float tile[64][65];
  const int t = threadIdx.x;
  if (blockIdx.x < 1024) {
    const int g = blockIdx.x >> 8;     // 0..3
    const float* W = g == 0 ? W0 : (g == 1 ? W1 : (g == 2 ? W2 : W3));
    __bf16* Wt = WtAll + (size_t)g * DM * DM;
    const int bid = blockIdx.x & 255;
    const int tk = bid >> 4;
    const int tn = bid & 15;
    const int r = t >> 4;
    const int c4 = (t & 15) << 2;
#pragma unroll
    for (int i = 0; i < 4; ++i) {
      const float4 v = *(const float4*)&W[(size_t)(tk * 64 + r + i * 16) * DM + tn * 64 + c4];
      tile[r + i * 16][c4 + 0] = v.x;
      tile[r + i * 16][c4 + 1] = v.y;
      tile[r + i * 16][c4 + 2] = v.z;
      tile[r + i * 16][c4 + 3] = v.w;
    }
    __syncthreads();
#pragma unroll
    for (int i = 0; i < 4; ++i) {
      const int n = r + i * 16;
      bf16x4 o = { (__bf16)tile[c4 + 0][n], (__bf16)tile[c4 + 1][n],
                   (__bf16)tile[c4 + 2][n], (__bf16)tile[c4 + 3][n] };
      *(bf16x4*)&Wt[(size_t)(tn * 64 + n) * DM + tk * 64 + c4] = o;
    }
  } else {
    const int n4 = (int)(OSZ / 4);
    int i = (blockIdx.x - 1024) * 256 + t;
    for (; i < n4; i += 2048 * 256) {
      const float4 v = ((const float4*)x)[i];
      bf16x4 o = { (__bf16)v.x, (__bf16)v.y, (__bf16)v.z, (__bf16)v.w };
      ((bf16x4*)xb)[i] = o;
    }
  }
}

// ------------------------------------------------- V bf16 -> slab-tiled VT2
__global__ __launch_bounds__(256, 4) void k_vtrans(const __bf16* __restrict__ vb,
                                                   __bf16* __restrict__ VT) {
  __shared__ __bf16 tile[128 * 72];   // row stride 72 bf16 (36 dw)
  const int t = threadIdx.x;
  const int bh = blockIdx.x >> 4;
  const int s0 = (blockIdx.x & 15) * 128;
  const int b = bh >> 4, h = bh & 15;

  {
    const int r = t >> 1, hh = t & 1;
    const __bf16* src = vb + (size_t)((s0 + r) * 4 + b) * DM + h * 64 + hh * 32;
    __bf16* dst = tile + r * 72 + hh * 32;
#pragma unroll
    for (int k = 0; k < 4; ++k)
      *(bf16x8*)(dst + k * 8) = *(const bf16x8*)(src + k * 8);
  }
  __syncthreads();

  const int l = t & 63;
  const int w = t >> 6;
  const int hf = l >> 5;
#pragma unroll
  for (int gi = 0; gi < 4; ++gi) {
    const int idx = w * 4 + gi;
    const int ktl = idx >> 3;
    const int fi = idx & 7;
    const int jc = fi >> 1, dh = fi & 1;
    const int d = dh * 32 + (l & 31);
    const int j8 = ktl * 64 + jc * 16 + hf * 8;
    bf16x8 pk;
#pragma unroll
    for (int jj = 0; jj < 8; ++jj) pk[jj] = tile[(j8 + jj) * 72 + d];
    const int kt_g = (blockIdx.x & 15) * 2 + ktl;
    *(bf16x8*)&VT[(size_t)(((bh * 32 + kt_g) * 8 + fi) * 64 + l) * 8] = pk;
  }
}

// ---------------------------------------------------------------- GEMM core
DEVI void gemm_tile_core(const __bf16* __restrict__ A, const __bf16* __restrict__ Bt,
                         char* Alds, char* Blds, int m0, int n0, int t,
                         f32x4 (&acc)[4][4]) {
  constexpr int K = 1024;
  const int l = t & 63;
  const int w = t >> 6;
  const int wr = w >> 1, wc = w & 1;

  int a_addr[2][4], b_addr[2][4];
#pragma unroll
  for (int s = 0; s < 2; ++s)
#pragma unroll
    for (int f = 0; f < 4; ++f) {
      const int ca = s * 64 + ((l >> 4) << 4);
      const int ra = wr * 64 + f * 16 + (l & 15);
      a_addr[s][f] = ra * 128 + (ca ^ ((ra & 7) << 4));
      const int rb = wc * 64 + f * 16 + (l & 15);
      b_addr[s][f] = rb * 128 + (ca ^ ((rb & 7) << 4));
    }

  int g_row[4], g_col[4];
#pragma unroll
  for (int i = 0; i < 4; ++i) {
    const int g = i * 256 + t;
    g_row[i] = g >> 3;
    g_col[i] = ((g & 7) ^ (g_row[i] & 7)) * 8;
  }

  for (int kt = 0; kt < K / 64; ++kt) {
#pragma unroll
    for (int i = 0; i < 4; ++i) {
      gload_lds16(A + (size_t)(m0 + g_row[i]) * K + kt * 64 + g_col[i],
                  Alds + (size_t)(i * 256 + t) * 16);
      gload_lds16(Bt + (size_t)(n0 + g_row[i]) * K + kt * 64 + g_col[i],
                  Blds + (size_t)(i * 256 + t) * 16);
    }
    __syncthreads();
#pragma unroll
    for (int s = 0; s < 2; ++s) {
      bf16x8 af[4], bfr[4];
#pragma unroll
      for (int f = 0; f < 4; ++f) {
        af[f]  = *(const bf16x8*)(Alds + a_addr[s][f]);
        bfr[f] = *(const bf16x8*)(Blds + b_addr[s][f]);
      }
      __builtin_amdgcn_s_setprio(1);
#pragma unroll
      for (int mi = 0; mi < 4; ++mi)
#pragma unroll
        for (int ni = 0; ni < 4; ++ni)
          acc[mi][ni] = __builtin_amdgcn_mfma_f32_16x16x32_bf16(af[mi], bfr[ni], acc[mi][ni], 0, 0, 0);
      __builtin_amdgcn_s_setprio(0);
    }
    __syncthreads();
  }
}

// Final GEMM: N=1024 single fp32 output
__global__ __launch_bounds__(256, 3) void k_gemm(
    const __bf16* __restrict__ A, const __bf16* __restrict__ Bt,
    const float* __restrict__ bias, float* __restrict__ Cf) {
  __shared__ alignas(16) char lds[32768];
  const int t = threadIdx.x;
  const int l = t & 63;
  const int w = t >> 6;
  const int n0 = (blockIdx.x & 7) * 128;
  const int m0 = (blockIdx.x >> 3) * 128;
  const int wr = w >> 1, wc = w & 1;

  f32x4 acc[4][4];
#pragma unroll
  for (int i = 0; i < 4; ++i)
#pragma unroll
    for (int j = 0; j < 4; ++j) acc[i][j] = (f32x4){0.f, 0.f, 0.f, 0.f};

  gemm_tile_core(A, Bt, lds, lds + 16384, m0, n0, t, acc);

  const int rowb = m0 + wr * 64 + ((l >> 4) << 2);
  const int colb = n0 + wc * 64 + (l & 15);
#pragma unroll
  for (int ni = 0; ni < 4; ++ni) {
    const float bv = bias[colb + ni * 16];
#pragma unroll
    for (int mi = 0; mi < 4; ++mi)
#pragma unroll
      for (int r = 0; r < 4; ++r)
        Cf[(size_t)(rowb + mi * 16 + r) * 1024 + colb + ni * 16] = acc[mi][ni][r] + bv;
  }
}

// Fused QKV GEMM + RoPE epilogue. Q output pre-scaled by SCALE*log2(e).
__global__ __launch_bounds__(256, 3) void k_gemm_qkv(
    const __bf16* __restrict__ A, const __bf16* __restrict__ Bt,
    const float* __restrict__ bq, const float* __restrict__ bk, const float* __restrict__ bv,
    const float* __restrict__ fc, const float* __restrict__ fs,
    float* __restrict__ ok, float* __restrict__ ov,
    __bf16* __restrict__ qr, __bf16* __restrict__ kr, __bf16* __restrict__ vb) {
  __shared__ alignas(16) char lds[32768];
  const int t = threadIdx.x;
  const int l = t & 63;
  const int w = t >> 6;
  const int nt = blockIdx.x % 24;
  const int n0 = nt * 128;
  const int m0 = (blockIdx.x / 24) * 128;
  const int wr = w >> 1, wc = w & 1;

  f32x4 acc[4][4];
#pragma unroll
  for (int i = 0; i < 4; ++i)
#pragma unroll
    for (int j = 0; j < 4; ++j) acc[i][j] = (f32x4){0.f, 0.f, 0.f, 0.f};

  gemm_tile_core(A, Bt, lds, lds + 16384, m0, n0, t, acc);

  const int grp = n0 >> 10;  // 0=q 1=k 2=v
  const int rowb = m0 + wr * 64 + ((l >> 4) << 2);
  const int colb = (n0 & 1023) + wc * 64 + (l & 15);

  if (grp == 2) {
#pragma unroll
    for (int ni = 0; ni < 4; ++ni) {
      const float bvv = bv[colb + ni * 16];
#pragma unroll
      for (int mi = 0; mi < 4; ++mi)
#pragma unroll
        for (int r = 0; r < 4; ++r) {
          const float v = acc[mi][ni][r] + bvv;
          const size_t idx = (size_t)(rowb + mi * 16 + r) * 1024 + colb + ni * 16;
          ov[idx] = v;
          vb[idx] = (__bf16)v;
        }
    }
  } else {
    const float* bias = grp == 0 ? bq : bk;
    __bf16* Rb = grp == 0 ? qr : kr;
    const float scl = grp == 0 ? SCL2E : 1.0f;   // fold softmax scale into Q
    const float sgn = (l & 1) ? 1.f : -1.f;
#pragma unroll
    for (int ni = 0; ni < 4; ++ni) {
      const int col = colb + ni * 16;
      const float bvv = bias[col];
      const int p = (col & 63) >> 1;
#pragma unroll
      for (int mi = 0; mi < 4; ++mi) {
        const int s_idx = (rowb + mi * 16) >> 2;
        const float cv = fc[s_idx * 32 + p] * scl;
        const float sv = fs[s_idx * 32 + p] * scl * sgn;
#pragma unroll
        for (int r = 0; r < 4; ++r) {
          const float v = acc[mi][ni][r] + bvv;
          if (grp == 1) ok[(size_t)(rowb + mi * 16 + r) * 1024 + col] = v;
          const float part = __shfl_xor(v, 1);
          Rb[(size_t)(rowb + mi * 16 + r) * 1024 + col] = (__bf16)(v * cv + part * sv);
        }
      }
    }
  }
}

// ---------------------------------------------------------------- flash attention v11 (banked)
static constexpr int FBUF11 = 16384;

__global__ __launch_bounds__(256, 4) void k_flash11(
    const __bf16* __restrict__ Q, const __bf16* __restrict__ Kr,
    const __bf16* __restrict__ VT, __bf16* __restrict__ O) {
  __shared__ alignas(16) char lds[2 * FBUF11];

  const int t = threadIdx.x, l = t & 63, w = t >> 6;
  const int hf = l >> 5;
  const int q32 = l & 31;
  const int swz = (blockIdx.x & 7) * 128 + (blockIdx.x >> 3);  // XCD-aware
  const int qt = swz & 15;
  const int bh = swz >> 4;
  const int b = bh >> 4, hd = bh & 15;

  const int qrow = qt * 128 + w * 32 + q32;

  bf16x8 qf[4];
#pragma unroll
  for (int kc = 0; kc < 4; ++kc)
    qf[kc] = *(const bf16x8*)(Q + (size_t)(qrow * 4 + b) * DM + hd * 64 + kc * 16 + hf * 8);

  const f32x16 Z = zero16();
  f32x16 acc0 = zero16(), acc1 = zero16();
  float l_run = 0.f;

  const size_t KSTRIDE = (size_t)64 * 4 * DM;
  const size_t VSTRIDE = (size_t)512 * 8;
  const __bf16* kp0 = Kr + (size_t)((t & 31) * 4 + b) * DM + hd * 64 + (t >> 5) * 8;
  const __bf16* kp1 = kp0 + (size_t)32 * 4 * DM;
  const __bf16* vp0 = VT + ((size_t)(bh * 32) * 512 + t) * 8;
  const __bf16* vp1 = vp0 + 256 * 8;

  char* const K0 = lds;
  char* const V0 = lds + 8192;
  char* const K1 = lds + FBUF11;
  char* const V1 = K1 + 8192;

#define STAGE11(Kn, Vn)                         \
  do {                                          \
    gload_lds16(kp0, (Kn) + t * 16);            \
    gload_lds16(kp1, (Kn) + 4096 + t * 16);     \
    gload_lds16(vp0, (Vn) + t * 16);            \
    gload_lds16(vp1, (Vn) + 4096 + t * 16);     \
    kp0 += KSTRIDE; kp1 += KSTRIDE;             \
    vp0 += VSTRIDE; vp1 += VSTRIDE;             \
  } while (0)

  auto PROCESS = [&](const char* Kl, const char* Vl) {
    const bf16x8 kf00 = *(const bf16x8*)(Kl + 0 * 1024 + l * 16);
    const bf16x8 kf10 = *(const bf16x8*)(Kl + 4 * 1024 + l * 16);
    __builtin_amdgcn_s_setprio(1);
    f32x16 s0 = __builtin_amdgcn_mfma_f32_32x32x16_bf16(kf00, qf[0], Z, 0, 0, 0);
    f32x16 s1 = __builtin_amdgcn_mfma_f32_32x32x16_bf16(kf10, qf[0], Z, 0, 0, 0);
#pragma unroll
    for (int kc = 1; kc < 4; ++kc) {
      const bf16x8 kf0 = *(const bf16x8*)(Kl + (0 * 4 + kc) * 1024 + l * 16);
      const bf16x8 kf1 = *(const bf16x8*)(Kl + (1 * 4 + kc) * 1024 + l * 16);
      s0 = __builtin_amdgcn_mfma_f32_32x32x16_bf16(kf0, qf[kc], s0, 0, 0, 0);
      s1 = __builtin_amdgcn_mfma_f32_32x32x16_bf16(kf1, qf[kc], s1, 0, 0, 0);
    }
    __builtin_amdgcn_s_setprio(0);

    f32x16 p0, p1;
#pragma unroll
    for (int r = 0; r < 16; ++r) {
      p0[r] = __builtin_amdgcn_exp2f(s0[r]);
      p1[r] = __builtin_amdgcn_exp2f(s1[r]);
    }

    const f2x8 P0 = __builtin_bit_cast(f2x8, p0);
    const f2x8 P1 = __builtin_bit_cast(f2x8, p1);
    f32x2 a8[8];
#pragma unroll
    for (int j = 0; j < 8; ++j) a8[j] = pk_add(P0.h[j], P1.h[j]);
#pragma unroll
    for (int j = 0; j < 4; ++j) a8[j] = pk_add(a8[j], a8[j + 4]);
    a8[0] = pk_add(a8[0], a8[2]);
    a8[1] = pk_add(a8[1], a8[3]);
    a8[0] = pk_add(a8[0], a8[1]);
    float rs = a8[0][0] + a8[0][1];
    {
      float tmp = rs;
      asm("v_permlane32_swap_b32 %0, %1" : "+v"(rs), "+v"(tmp));
      rs = rs + tmp;
    }
    l_run += rs;

    unsigned pkw[16];
#pragma unroll
    for (int j = 0; j < 8; ++j) {
      pkw[j]     = pack_bf16(P0.h[j][0], P0.h[j][1]);
      pkw[8 + j] = pack_bf16(P1.h[j][0], P1.h[j][1]);
    }

#pragma unroll
    for (int c = 0; c < 2; ++c)
#pragma unroll
      for (int jc2 = 0; jc2 < 2; ++jc2) {
        unsigned w0 = pkw[c * 8 + 4 * jc2 + 0], w2 = pkw[c * 8 + 4 * jc2 + 2];
        unsigned w1 = pkw[c * 8 + 4 * jc2 + 1], w3 = pkw[c * 8 + 4 * jc2 + 3];
        asm("v_permlane32_swap_b32 %0, %1" : "+v"(w0), "+v"(w2));
        asm("v_permlane32_swap_b32 %0, %1" : "+v"(w1), "+v"(w3));
        const u32x4 pw = { w0, w1, w2, w3 };
        const bf16x8 pf = __builtin_bit_cast(bf16x8, pw);
        const int jc = c * 2 + jc2;
        const bf16x8 vf0 = *(const bf16x8*)(Vl + (jc * 2 + 0) * 1024 + l * 16);
        const bf16x8 vf1 = *(const bf16x8*)(Vl + (jc * 2 + 1) * 1024 + l * 16);
        __builtin_amdgcn_s_setprio(1);
        acc0 = __builtin_amdgcn_mfma_f32_32x32x16_bf16(vf0, pf, acc0, 0, 0, 0);
        acc1 = __builtin_amdgcn_mfma_f32_32x32x16_bf16(vf1, pf, acc1, 0, 0, 0);
        __builtin_amdgcn_s_setprio(0);
      }
  };

  STAGE11(K0, V0);

  for (int kt = 0; kt < QLEN / 64; kt += 2) {
    __syncthreads();
    STAGE11(K1, V1);
    PROCESS(K0, V0);
    __syncthreads();
    if (kt + 2 < QLEN / 64) STAGE11(K0, V0);
    PROCESS(K1, V1);
  }
#undef STAGE11

  const float inv = 1.0f / l_run;
#pragma unroll
  for (int g = 0; g < 4; ++g) {
    {
      const int d0 = 8 * g + 4 * hf;
      bf16x4 o4 = { (__bf16)(acc0[4 * g + 0] * inv), (__bf16)(acc0[4 * g + 1] * inv),
                    (__bf16)(acc0[4 * g + 2] * inv), (__bf16)(acc0[4 * g + 3] * inv) };
      *(bf16x4*)&O[(size_t)(qrow * 4 + b) * DM + hd * 64 + d0] = o4;
    }
    {
      const int d0 = 32 + 8 * g + 4 * hf;
      bf16x4 o4 = { (__bf16)(acc1[4 * g + 0] * inv), (__bf16)(acc1[4 * g + 1] * inv),
                    (__bf16)(acc1[4 * g + 2] * inv), (__bf16)(acc1[4 * g + 3] * inv) };
      *(bf16x4*)&O[(size_t)(qrow * 4 + b) * DM + hd * 64 + d0] = o4;
    }
  }
}

// ---------------------------------------------------------------- launch
extern "C" void kernel_launch(void* const* d_in, const int* in_sizes, int n_in,
                              void* d_out, int out_size, void* d_ws, size_t ws_size,
                              hipStream_t stream) {
  const float* x    = (const float*)d_in[0];
  const float* fcos = (const float*)d_in[1];
  const float* fsin = (const float*)d_in[2];
  const float* Wq   = (const float*)d_in[3];
  const float* bq   = (const float*)d_in[4];
  const float* Wk   = (const float*)d_in[5];
  const float* bk   = (const float*)d_in[6];
  const float* Wv   = (const float*)d_in[7];
  const float* bv   = (const float*)d_in[8];
  const float* Wo   = (const float*)d_in[9];
  const float* bo   = (const float*)d_in[10];

  float* out_o = (float*)d_out;
  float* out_k = out_o + OSZ;
  float* out_v = out_o + 2 * OSZ;

  char* ws = (char*)d_ws;
  __bf16* xb  = (__bf16*)(ws);              // 16MB; reused as VT2 after QKV GEMM
  __bf16* VT  = (__bf16*)(ws);
  __bf16* wqt = (__bf16*)(ws + 16777216);   // wqt|wkt|wvt|wot contiguous
  __bf16* wot = (__bf16*)(ws + 23068672);
  __bf16* qr  = (__bf16*)(ws + 25165824);
  __bf16* kr  = (__bf16*)(ws + 41943040);
  __bf16* vb  = (__bf16*)(ws + 58720256);
  __bf16* ao  = (__bf16*)(ws + 75497472);

  k_prep<<<3072, 256, 0, stream>>>(x, xb, Wq, Wk, Wv, Wo, wqt);

  k_gemm_qkv<<<1536, 256, 0, stream>>>(xb, wqt, bq, bk, bv, fcos, fsin,
                                       out_k, out_v, qr, kr, vb);

  k_vtrans<<<1024, 256, 0, stream>>>(vb, VT);

  k_flash11<<<1024, 256, 0, stream>>>(qr, kr, VT, ao);

  k_gemm<<<512, 256, 0, stream>>>(ao, wot, bo, out_o);
}

// Round 15
// 192.265 us; speedup vs baseline: 1.2223x; 1.0182x over previous
//
#include <hip/hip_runtime.h>

typedef __attribute__((ext_vector_type(2))) float f32x2;
typedef __attribute__((ext_vector_type(4))) float f32x4;
typedef __attribute__((ext_vector_type(16))) float f32x16;
typedef __attribute__((ext_vector_type(8))) __bf16 bf16x8;
typedef __attribute__((ext_vector_type(4))) __bf16 bf16x4;
typedef __attribute__((ext_vector_type(2))) __bf16 bf16x2;
typedef __attribute__((ext_vector_type(4))) unsigned int u32x4;

#define DEVI __device__ __forceinline__

static constexpr int QLEN = 2048, BSZ = 4, DM = 1024, NH = 16, DH = 64;
static constexpr int MROWS = QLEN * BSZ;       // 8192
static constexpr long OSZ  = (long)MROWS * DM; // 8388608 elements per output tensor
static constexpr float SCL2E = 0.125f * 1.4426950408889634f; // SCALE * log2(e), folded into Q

DEVI void gload_lds16(const void* g, void* l) {
  __builtin_amdgcn_global_load_lds(
      (__attribute__((address_space(1))) void*)(size_t)g,
      (__attribute__((address_space(3))) void*)l, 16, 0, 0);
}

DEVI f32x16 zero16() {
  f32x16 v;
#pragma unroll
  for (int i = 0; i < 16; ++i) v[i] = 0.f;
  return v;
}

DEVI unsigned pack_bf16(float lo, float hi) {
  bf16x2 v = { (__bf16)lo, (__bf16)hi };
  return __builtin_bit_cast(unsigned, v);
}

struct f2x8 { f32x2 h[8]; };

DEVI f32x2 pk_add(f32x2 a, f32x2 b) {
  f32x2 d;
  asm("v_pk_add_f32 %0, %1, %2" : "=v"(d) : "v"(a), "v"(b));
  return d;
}

// ------------------------------------------------- prep: x fp32->bf16 + 4x wtrans
__global__ void k_prep(const float* __restrict__ x, __bf16* __restrict__ xb,
                       const float* __restrict__ W0, const float* __restrict__ W1,
                       const float* __restrict__ W2, const float* __restrict__ W3,
                       __bf16* __restrict__ WtAll) {
  __shared__ float tile[64][65];
  const int t = threadIdx.x;
  if (blockIdx.x < 1024) {
    const int g = blockIdx.x >> 8;     // 0..3
    const float* W = g == 0 ? W0 : (g == 1 ? W1 : (g == 2 ? W2 : W3));
    __bf16* Wt = WtAll + (size_t)g * DM * DM;
    const int bid = blockIdx.x & 255;
    const int tk = bid >> 4;
    const int tn = bid & 15;
    const int r = t >> 4;
    const int c4 = (t & 15) << 2;
#pragma unroll
    for (int i = 0; i < 4; ++i) {
      const float4 v = *(const float4*)&W[(size_t)(tk * 64 + r + i * 16) * DM + tn * 64 + c4];
      tile[r + i * 16][c4 + 0] = v.x;
      tile[r + i * 16][c4 + 1] = v.y;
      tile[r + i * 16][c4 + 2] = v.z;
      tile[r + i * 16][c4 + 3] = v.w;
    }
    __syncthreads();
#pragma unroll
    for (int i = 0; i < 4; ++i) {
      const int n = r + i * 16;
      bf16x4 o = { (__bf16)tile[c4 + 0][n], (__bf16)tile[c4 + 1][n],
                   (__bf16)tile[c4 + 2][n], (__bf16)tile[c4 + 3][n] };
      *(bf16x4*)&Wt[(size_t)(tn * 64 + n) * DM + tk * 64 + c4] = o;
    }
  } else {
    const int n4 = (int)(OSZ / 4);
    int i = (blockIdx.x - 1024) * 256 + t;
    for (; i < n4; i += 2048 * 256) {
      const float4 v = ((const float4*)x)[i];
      bf16x4 o = { (__bf16)v.x, (__bf16)v.y, (__bf16)v.z, (__bf16)v.w };
      ((bf16x4*)xb)[i] = o;
    }
  }
}

// ------------------------------------------------- V bf16 -> slab-tiled VT2
__global__ __launch_bounds__(256, 4) void k_vtrans(const __bf16* __restrict__ vb,
                                                   __bf16* __restrict__ VT) {
  __shared__ __bf16 tile[128 * 72];   // row stride 72 bf16 (36 dw)
  const int t = threadIdx.x;
  const int bh = blockIdx.x >> 4;
  const int s0 = (blockIdx.x & 15) * 128;
  const int b = bh >> 4, h = bh & 15;

  {
    const int r = t >> 1, hh = t & 1;
    const __bf16* src = vb + (size_t)((s0 + r) * 4 + b) * DM + h * 64 + hh * 32;
    __bf16* dst = tile + r * 72 + hh * 32;
#pragma unroll
    for (int k = 0; k < 4; ++k)
      *(bf16x8*)(dst + k * 8) = *(const bf16x8*)(src + k * 8);
  }
  __syncthreads();

  const int l = t & 63;
  const int w = t >> 6;
  const int hf = l >> 5;
#pragma unroll
  for (int gi = 0; gi < 4; ++gi) {
    const int idx = w * 4 + gi;
    const int ktl = idx >> 3;
    const int fi = idx & 7;
    const int jc = fi >> 1, dh = fi & 1;
    const int d = dh * 32 + (l & 31);
    const int j8 = ktl * 64 + jc * 16 + hf * 8;
    bf16x8 pk;
#pragma unroll
    for (int jj = 0; jj < 8; ++jj) pk[jj] = tile[(j8 + jj) * 72 + d];
    const int kt_g = (blockIdx.x & 15) * 2 + ktl;
    *(bf16x8*)&VT[(size_t)(((bh * 32 + kt_g) * 8 + fi) * 64 + l) * 8] = pk;
  }
}

// ---------------------------------------------------------------- GEMM core
DEVI void gemm_tile_core(const __bf16* __restrict__ A, const __bf16* __restrict__ Bt,
                         char* Alds, char* Blds, int m0, int n0, int t,
                         f32x4 (&acc)[4][4]) {
  constexpr int K = 1024;
  const int l = t & 63;
  const int w = t >> 6;
  const int wr = w >> 1, wc = w & 1;

  int a_addr[2][4], b_addr[2][4];
#pragma unroll
  for (int s = 0; s < 2; ++s)
#pragma unroll
    for (int f = 0; f < 4; ++f) {
      const int ca = s * 64 + ((l >> 4) << 4);
      const int ra = wr * 64 + f * 16 + (l & 15);
      a_addr[s][f] = ra * 128 + (ca ^ ((ra & 7) << 4));
      const int rb = wc * 64 + f * 16 + (l & 15);
      b_addr[s][f] = rb * 128 + (ca ^ ((rb & 7) << 4));
    }

  int g_row[4], g_col[4];
#pragma unroll
  for (int i = 0; i < 4; ++i) {
    const int g = i * 256 + t;
    g_row[i] = g >> 3;
    g_col[i] = ((g & 7) ^ (g_row[i] & 7)) * 8;
  }

  for (int kt = 0; kt < K / 64; ++kt) {
#pragma unroll
    for (int i = 0; i < 4; ++i) {
      gload_lds16(A + (size_t)(m0 + g_row[i]) * K + kt * 64 + g_col[i],
                  Alds + (size_t)(i * 256 + t) * 16);
      gload_lds16(Bt + (size_t)(n0 + g_row[i]) * K + kt * 64 + g_col[i],
                  Blds + (size_t)(i * 256 + t) * 16);
    }
    __syncthreads();
#pragma unroll
    for (int s = 0; s < 2; ++s) {
      bf16x8 af[4], bfr[4];
#pragma unroll
      for (int f = 0; f < 4; ++f) {
        af[f]  = *(const bf16x8*)(Alds + a_addr[s][f]);
        bfr[f] = *(const bf16x8*)(Blds + b_addr[s][f]);
      }
      __builtin_amdgcn_s_setprio(1);
#pragma unroll
      for (int mi = 0; mi < 4; ++mi)
#pragma unroll
        for (int ni = 0; ni < 4; ++ni)
          acc[mi][ni] = __builtin_amdgcn_mfma_f32_16x16x32_bf16(af[mi], bfr[ni], acc[mi][ni], 0, 0, 0);
      __builtin_amdgcn_s_setprio(0);
    }
    __syncthreads();
  }
}

// Final GEMM: N=1024 single fp32 output.
// 2-D XCD swizzle: XCD = (n%4)*2 + (m%2) -> B-panels stay per-XCD resident
// (2 x 256KB), A-tile XCD-spread 8 -> 4 (halves A re-fetch).
__global__ __launch_bounds__(256, 3) void k_gemm(
    const __bf16* __restrict__ A, const __bf16* __restrict__ Bt,
    const float* __restrict__ bias, float* __restrict__ Cf) {
  __shared__ alignas(16) char lds[32768];
  const int t = threadIdx.x;
  const int l = t & 63;
  const int w = t >> 6;
  const int x = blockIdx.x & 7;        // XCD (dispatch round-robin)
  const int j = blockIdx.x >> 3;       // 0..63
  const int nq = x >> 1, mp = x & 1;
  const int n0 = (nq + (j & 1) * 4) * 128;        // n%4 == nq
  const int m0 = ((j >> 1) * 2 + mp) * 128;       // m%2 == mp
  const int wr = w >> 1, wc = w & 1;

  f32x4 acc[4][4];
#pragma unroll
  for (int i = 0; i < 4; ++i)
#pragma unroll
    for (int jj = 0; jj < 4; ++jj) acc[i][jj] = (f32x4){0.f, 0.f, 0.f, 0.f};

  gemm_tile_core(A, Bt, lds, lds + 16384, m0, n0, t, acc);

  const int rowb = m0 + wr * 64 + ((l >> 4) << 2);
  const int colb = n0 + wc * 64 + (l & 15);
#pragma unroll
  for (int ni = 0; ni < 4; ++ni) {
    const float bv = bias[colb + ni * 16];
#pragma unroll
    for (int mi = 0; mi < 4; ++mi)
#pragma unroll
      for (int r = 0; r < 4; ++r)
        Cf[(size_t)(rowb + mi * 16 + r) * 1024 + colb + ni * 16] = acc[mi][ni][r] + bv;
  }
}

// Fused QKV GEMM + RoPE epilogue. Q output pre-scaled by SCALE*log2(e).
// 2-D XCD swizzle: XCD = (nt%4)*2 + (mtile%2) -> per-XCD B-panel working set
// 6 x 256KB = 1.5MB (L2-resident), A-tile XCD-spread 8 -> 4.
__global__ __launch_bounds__(256, 3) void k_gemm_qkv(
    const __bf16* __restrict__ A, const __bf16* __restrict__ Bt,
    const float* __restrict__ bq, const float* __restrict__ bk, const float* __restrict__ bv,
    const float* __restrict__ fc, const float* __restrict__ fs,
    float* __restrict__ ok, float* __restrict__ ov,
    __bf16* __restrict__ qr, __bf16* __restrict__ kr, __bf16* __restrict__ vb) {
  __shared__ alignas(16) char lds[32768];
  const int t = threadIdx.x;
  const int l = t & 63;
  const int w = t >> 6;
  const int x = blockIdx.x & 7;        // XCD
  const int j = blockIdx.x >> 3;       // 0..191
  const int n4 = x >> 1, mp = x & 1;
  const int nt = (j % 6) * 4 + n4;     // 0..23, nt%4 == n4
  const int n0 = nt * 128;
  const int m0 = ((j / 6) * 2 + mp) * 128;  // 0..63 tiles, m%2 == mp
  const int wr = w >> 1, wc = w & 1;

  f32x4 acc[4][4];
#pragma unroll
  for (int i = 0; i < 4; ++i)
#pragma unroll
    for (int jj = 0; jj < 4; ++jj) acc[i][jj] = (f32x4){0.f, 0.f, 0.f, 0.f};

  gemm_tile_core(A, Bt, lds, lds + 16384, m0, n0, t, acc);

  const int grp = n0 >> 10;  // 0=q 1=k 2=v
  const int rowb = m0 + wr * 64 + ((l >> 4) << 2);
  const int colb = (n0 & 1023) + wc * 64 + (l & 15);

  if (grp == 2) {
#pragma unroll
    for (int ni = 0; ni < 4; ++ni) {
      const float bvv = bv[colb + ni * 16];
#pragma unroll
      for (int mi = 0; mi < 4; ++mi)
#pragma unroll
        for (int r = 0; r < 4; ++r) {
          const float v = acc[mi][ni][r] + bvv;
          const size_t idx = (size_t)(rowb + mi * 16 + r) * 1024 + colb + ni * 16;
          ov[idx] = v;
          vb[idx] = (__bf16)v;
        }
    }
  } else {
    const float* bias = grp == 0 ? bq : bk;
    __bf16* Rb = grp == 0 ? qr : kr;
    const float scl = grp == 0 ? SCL2E : 1.0f;   // fold softmax scale into Q
    const float sgn = (l & 1) ? 1.f : -1.f;
#pragma unroll
    for (int ni = 0; ni < 4; ++ni) {
      const int col = colb + ni * 16;
      const float bvv = bias[col];
      const int p = (col & 63) >> 1;
#pragma unroll
      for (int mi = 0; mi < 4; ++mi) {
        const int s_idx = (rowb + mi * 16) >> 2;
        const float cv = fc[s_idx * 32 + p] * scl;
        const float sv = fs[s_idx * 32 + p] * scl * sgn;
#pragma unroll
        for (int r = 0; r < 4; ++r) {
          const float v = acc[mi][ni][r] + bvv;
          if (grp == 1) ok[(size_t)(rowb + mi * 16 + r) * 1024 + col] = v;
          const float part = __shfl_xor(v, 1);
          Rb[(size_t)(rowb + mi * 16 + r) * 1024 + col] = (__bf16)(v * cv + part * sv);
        }
      }
    }
  }
}

// ---------------------------------------------------------------- flash attention v11 (banked)
static constexpr int FBUF11 = 16384;

__global__ __launch_bounds__(256, 4) void k_flash11(
    const __bf16* __restrict__ Q, const __bf16* __restrict__ Kr,
    const __bf16* __restrict__ VT, __bf16* __restrict__ O) {
  __shared__ alignas(16) char lds[2 * FBUF11];

  const int t = threadIdx.x, l = t & 63, w = t >> 6;
  const int hf = l >> 5;
  const int q32 = l & 31;
  const int swz = (blockIdx.x & 7) * 128 + (blockIdx.x >> 3);  // XCD-aware
  const int qt = swz & 15;
  const int bh = swz >> 4;
  const int b = bh >> 4, hd = bh & 15;

  const int qrow = qt * 128 + w * 32 + q32;

  bf16x8 qf[4];
#pragma unroll
  for (int kc = 0; kc < 4; ++kc)
    qf[kc] = *(const bf16x8*)(Q + (size_t)(qrow * 4 + b) * DM + hd * 64 + kc * 16 + hf * 8);

  const f32x16 Z = zero16();
  f32x16 acc0 = zero16(), acc1 = zero16();
  float l_run = 0.f;

  const size_t KSTRIDE = (size_t)64 * 4 * DM;
  const size_t VSTRIDE = (size_t)512 * 8;
  const __bf16* kp0 = Kr + (size_t)((t & 31) * 4 + b) * DM + hd * 64 + (t >> 5) * 8;
  const __bf16* kp1 = kp0 + (size_t)32 * 4 * DM;
  const __bf16* vp0 = VT + ((size_t)(bh * 32) * 512 + t) * 8;
  const __bf16* vp1 = vp0 + 256 * 8;

  char* const K0 = lds;
  char* const V0 = lds + 8192;
  char* const K1 = lds + FBUF11;
  char* const V1 = K1 + 8192;

#define STAGE11(Kn, Vn)                         \
  do {                                          \
    gload_lds16(kp0, (Kn) + t * 16);            \
    gload_lds16(kp1, (Kn) + 4096 + t * 16);     \
    gload_lds16(vp0, (Vn) + t * 16);            \
    gload_lds16(vp1, (Vn) + 4096 + t * 16);     \
    kp0 += KSTRIDE; kp1 += KSTRIDE;             \
    vp0 += VSTRIDE; vp1 += VSTRIDE;             \
  } while (0)

  auto PROCESS = [&](const char* Kl, const char* Vl) {
    const bf16x8 kf00 = *(const bf16x8*)(Kl + 0 * 1024 + l * 16);
    const bf16x8 kf10 = *(const bf16x8*)(Kl + 4 * 1024 + l * 16);
    __builtin_amdgcn_s_setprio(1);
    f32x16 s0 = __builtin_amdgcn_mfma_f32_32x32x16_bf16(kf00, qf[0], Z, 0, 0, 0);
    f32x16 s1 = __builtin_amdgcn_mfma_f32_32x32x16_bf16(kf10, qf[0], Z, 0, 0, 0);
#pragma unroll
    for (int kc = 1; kc < 4; ++kc) {
      const bf16x8 kf0 = *(const bf16x8*)(Kl + (0 * 4 + kc) * 1024 + l * 16);
      const bf16x8 kf1 = *(const bf16x8*)(Kl + (1 * 4 + kc) * 1024 + l * 16);
      s0 = __builtin_amdgcn_mfma_f32_32x32x16_bf16(kf0, qf[kc], s0, 0, 0, 0);
      s1 = __builtin_amdgcn_mfma_f32_32x32x16_bf16(kf1, qf[kc], s1, 0, 0, 0);
    }
    __builtin_amdgcn_s_setprio(0);

    f32x16 p0, p1;
#pragma unroll
    for (int r = 0; r < 16; ++r) {
      p0[r] = __builtin_amdgcn_exp2f(s0[r]);
      p1[r] = __builtin_amdgcn_exp2f(s1[r]);
    }

    const f2x8 P0 = __builtin_bit_cast(f2x8, p0);
    const f2x8 P1 = __builtin_bit_cast(f2x8, p1);
    f32x2 a8[8];
#pragma unroll
    for (int j = 0; j < 8; ++j) a8[j] = pk_add(P0.h[j], P1.h[j]);
#pragma unroll
    for (int j = 0; j < 4; ++j) a8[j] = pk_add(a8[j], a8[j + 4]);
    a8[0] = pk_add(a8[0], a8[2]);
    a8[1] = pk_add(a8[1], a8[3]);
    a8[0] = pk_add(a8[0], a8[1]);
    float rs = a8[0][0] + a8[0][1];
    {
      float tmp = rs;
      asm("v_permlane32_swap_b32 %0, %1" : "+v"(rs), "+v"(tmp));
      rs = rs + tmp;
    }
    l_run += rs;

    unsigned pkw[16];
#pragma unroll
    for (int j = 0; j < 8; ++j) {
      pkw[j]     = pack_bf16(P0.h[j][0], P0.h[j][1]);
      pkw[8 + j] = pack_bf16(P1.h[j][0], P1.h[j][1]);
    }

#pragma unroll
    for (int c = 0; c < 2; ++c)
#pragma unroll
      for (int jc2 = 0; jc2 < 2; ++jc2) {
        unsigned w0 = pkw[c * 8 + 4 * jc2 + 0], w2 = pkw[c * 8 + 4 * jc2 + 2];
        unsigned w1 = pkw[c * 8 + 4 * jc2 + 1], w3 = pkw[c * 8 + 4 * jc2 + 3];
        asm("v_permlane32_swap_b32 %0, %1" : "+v"(w0), "+v"(w2));
        asm("v_permlane32_swap_b32 %0, %1" : "+v"(w1), "+v"(w3));
        const u32x4 pw = { w0, w1, w2, w3 };
        const bf16x8 pf = __builtin_bit_cast(bf16x8, pw);
        const int jc = c * 2 + jc2;
        const bf16x8 vf0 = *(const bf16x8*)(Vl + (jc * 2 + 0) * 1024 + l * 16);
        const bf16x8 vf1 = *(const bf16x8*)(Vl + (jc * 2 + 1) * 1024 + l * 16);
        __builtin_amdgcn_s_setprio(1);
        acc0 = __builtin_amdgcn_mfma_f32_32x32x16_bf16(vf0, pf, acc0, 0, 0, 0);
        acc1 = __builtin_amdgcn_mfma_f32_32x32x16_bf16(vf1, pf, acc1, 0, 0, 0);
        __builtin_amdgcn_s_setprio(0);
      }
  };

  STAGE11(K0, V0);

  for (int kt = 0; kt < QLEN / 64; kt += 2) {
    __syncthreads();
    STAGE11(K1, V1);
    PROCESS(K0, V0);
    __syncthreads();
    if (kt + 2 < QLEN / 64) STAGE11(K0, V0);
    PROCESS(K1, V1);
  }
#undef STAGE11

  const float inv = 1.0f / l_run;
#pragma unroll
  for (int g = 0; g < 4; ++g) {
    {
      const int d0 = 8 * g + 4 * hf;
      bf16x4 o4 = { (__bf16)(acc0[4 * g + 0] * inv), (__bf16)(acc0[4 * g + 1] * inv),
                    (__bf16)(acc0[4 * g + 2] * inv), (__bf16)(acc0[4 * g + 3] * inv) };
      *(bf16x4*)&O[(size_t)(qrow * 4 + b) * DM + hd * 64 + d0] = o4;
    }
    {
      const int d0 = 32 + 8 * g + 4 * hf;
      bf16x4 o4 = { (__bf16)(acc1[4 * g + 0] * inv), (__bf16)(acc1[4 * g + 1] * inv),
                    (__bf16)(acc1[4 * g + 2] * inv), (__bf16)(acc1[4 * g + 3] * inv) };
      *(bf16x4*)&O[(size_t)(qrow * 4 + b) * DM + hd * 64 + d0] = o4;
    }
  }
}

// ---------------------------------------------------------------- launch
extern "C" void kernel_launch(void* const* d_in, const int* in_sizes, int n_in,
                              void* d_out, int out_size, void* d_ws, size_t ws_size,
                              hipStream_t stream) {
  const float* x    = (const float*)d_in[0];
  const float* fcos = (const float*)d_in[1];
  const float* fsin = (const float*)d_in[2];
  const float* Wq   = (const float*)d_in[3];
  const float* bq   = (const float*)d_in[4];
  const float* Wk   = (const float*)d_in[5];
  const float* bk   = (const float*)d_in[6];
  const float* Wv   = (const float*)d_in[7];
  const float* bv   = (const float*)d_in[8];
  const float* Wo   = (const float*)d_in[9];
  const float* bo   = (const float*)d_in[10];

  float* out_o = (float*)d_out;
  float* out_k = out_o + OSZ;
  float* out_v = out_o + 2 * OSZ;

  char* ws = (char*)d_ws;
  __bf16* xb  = (__bf16*)(ws);              // 16MB; reused as VT2 after QKV GEMM
  __bf16* VT  = (__bf16*)(ws);
  __bf16* wqt = (__bf16*)(ws + 16777216);   // wqt|wkt|wvt|wot contiguous
  __bf16* wot = (__bf16*)(ws + 23068672);
  __bf16* qr  = (__bf16*)(ws + 25165824);
  __bf16* kr  = (__bf16*)(ws + 41943040);
  __bf16* vb  = (__bf16*)(ws + 58720256);
  __bf16* ao  = (__bf16*)(ws + 75497472);

  k_prep<<<3072, 256, 0, stream>>>(x, xb, Wq, Wk, Wv, Wo, wqt);

  k_gemm_qkv<<<1536, 256, 0, stream>>>(xb, wqt, bq, bk, bv, fcos, fsin,
                                       out_k, out_v, qr, kr, vb);

  k_vtrans<<<1024, 256, 0, stream>>>(vb, VT);

  k_flash11<<<1024, 256, 0, stream>>>(qr, kr, VT, ao);

  k_gemm<<<512, 256, 0, stream>>>(ao, wot, bo, out_o);
}